// Round 4
// baseline (144050.159 us; speedup 1.0000x reference)
//
#include <hip/hip_runtime.h>

// Problem constants: N=1024, K=32, F=8192, E=64, H1=128, H2=64, T=3

typedef float f32x4 __attribute__((ext_vector_type(4)));
typedef float f32x2 __attribute__((ext_vector_type(2)));

// ---------------------------------------------------------------------------
// K1: G0 = X @ W_emb (f64 accumulation), feat0 = relu(G0 + b_emb), out=feat0
// ---------------------------------------------------------------------------
__global__ __launch_bounds__(256) void k_embed(
    const float* __restrict__ X, const float* __restrict__ W_emb,
    const float* __restrict__ b_emb,
    float* __restrict__ G0, float* __restrict__ feat0, float* __restrict__ out)
{
  const int t = threadIdx.x;
  const int j = t & 63;
  const int node = (blockIdx.x << 2) + (t >> 6);
  const float* __restrict__ xr = X + (size_t)node * 8192;
  const float* __restrict__ wp = W_emb + j;
  double a0 = 0.0, a1 = 0.0, a2 = 0.0, a3 = 0.0;
  for (int f = 0; f < 8192; f += 4) {
    float x0 = xr[f + 0], x1 = xr[f + 1], x2 = xr[f + 2], x3 = xr[f + 3];
    a0 = fma((double)x0, (double)wp[(f + 0) << 6], a0);
    a1 = fma((double)x1, (double)wp[(f + 1) << 6], a1);
    a2 = fma((double)x2, (double)wp[(f + 2) << 6], a2);
    a3 = fma((double)x3, (double)wp[(f + 3) << 6], a3);
  }
  float g = (float)((a0 + a1) + (a2 + a3));
  const int o = node * 64 + j;
  G0[o] = g;
  float f0 = fmaxf(g + b_emb[j], 0.0f);
  feat0[o] = f0;
  out[o] = f0;
}

// ---------------------------------------------------------------------------
// K2: Y0 = feat0 @ W1b (W1 rows 64..127); Y = Y0 working copy
// ---------------------------------------------------------------------------
__global__ __launch_bounds__(128) void k_y0(
    const float* __restrict__ feat0, const float* __restrict__ W1,
    float* __restrict__ Y0, float* __restrict__ Y)
{
  const int c = threadIdx.x;
  const int i = blockIdx.x;
  const float* __restrict__ fr = feat0 + i * 64;
  float acc = 0.0f;
  #pragma unroll 8
  for (int e = 0; e < 64; ++e)
    acc = fmaf(fr[e], W1[(64 + e) * 128 + c], acc);
  Y0[i * 128 + c] = acc;
  Y[i * 128 + c] = acc;
}

// ---------------------------------------------------------------------------
// K3: serial chain. 256 threads (4 waves). W2 lives in LDS, transposed +
// chunk-XOR swizzled (bank-conflict-free b128 reads). Each wave tiles 8 (+1)
// h1 rows per W2 pass -> 8-9x W2 reuse per read. All FMA chain orders are
// bit-identical to the previously passing kernel (same argmax decisions).
// ---------------------------------------------------------------------------
__global__ __launch_bounds__(256, 1) void k_serial(
    const int* __restrict__ neighbors,
    const float* __restrict__ W1, const float* __restrict__ b1,
    const float* __restrict__ W2, const float* __restrict__ b2,
    const float* __restrict__ W_lk, const float* __restrict__ b_lk,
    const float* __restrict__ W_act, const float* __restrict__ b_act,
    const float* __restrict__ b_emb,
    const float* __restrict__ G0, const float* __restrict__ feat0,
    const float* __restrict__ Y0, float* __restrict__ Y,
    float* __restrict__ feature)   // == d_out
{
  __shared__ __align__(16) float W1s[128 * 128];   // 64 KB
  __shared__ __align__(16) float W2Ts[64][128];    // 32 KB, swizzled
  __shared__ __align__(16) float Yl[32][128];      // 16 KB
  __shared__ __align__(16) float G0l[32][64];      // 8 KB
  __shared__ __align__(16) float f0l[32][64];      // 8 KB
  __shared__ __align__(16) float h1s[33][128];     // 16.5 KB
  __shared__ __align__(16) float h2s[33][64];      // 8.25 KB
  __shared__ __align__(16) float a1s[128];
  __shared__ __align__(16) float fis[64];
  __shared__ float gis[64], sumg[64];
  __shared__ float b1s[128], b2s[64], bembs[64], wlks[64], wacts[128];
  __shared__ float lks[33];
  __shared__ int idxs[32];
  __shared__ int s_u, s_upd, s_utc, s_done;
  __shared__ unsigned s_valid, s_mu, s_mi;
  __shared__ float s_cntf;

  const int t = threadIdx.x;
  const int lane = t & 63;
  const int wave = t >> 6;

  // ---- one-time staging ----
  #pragma unroll
  for (int m = 0; m < 16; ++m) {
    int i4 = (m * 256 + t) << 2;
    *(float4*)&W1s[i4] = *(const float4*)&W1[i4];
  }
  // W2Ts[j][ (( (c>>2) ^ (j&7) ) << 2) + (c&3) ] = W2[c*64 + j]
  for (int e = t; e < 8192; e += 256) {
    int c = e >> 6, j = e & 63;
    W2Ts[j][(((c >> 2) ^ (j & 7)) << 2) + (c & 3)] = W2[e];
  }
  if (t < 128) { b1s[t] = b1[t]; wacts[t] = W_act[t]; }
  if (t < 64) { b2s[t] = b2[t]; bembs[t] = b_emb[t]; wlks[t] = W_lk[t]; }
  const float blkv = b_lk[0];
  const float ba0 = b_act[0];
  const float ba1 = b_act[1];
  const int wsw = (lane & 7) << 2;   // W2 swizzle base (float offset of XOR)
  __syncthreads();

  for (int i = 0; i < 1024; ++i) {
    // ---- phase0: per-node prefetch into LDS ----
    #pragma unroll
    for (int p = 0; p < 4; ++p) {
      int fi = (p << 8) + t;               // 0..1023
      int k = fi >> 5;
      int c4 = (fi & 31) << 2;
      int v = neighbors[(i << 5) + k];
      *(float4*)&Yl[k][c4] = *(const float4*)&Y[v * 128 + c4];
    }
    #pragma unroll
    for (int p = 0; p < 2; ++p) {
      int fi = (p << 8) + t;               // 0..511
      int k = fi >> 4;
      int c4 = (fi & 15) << 2;
      int v = neighbors[(i << 5) + k];
      *(float4*)&G0l[k][c4] = *(const float4*)&G0[v * 64 + c4];
      *(float4*)&f0l[k][c4] = *(const float4*)&feat0[v * 64 + c4];
    }
    if (t < 64) { fis[t] = feature[i * 64 + t]; gis[t] = G0[i * 64 + t]; sumg[t] = 0.f; }
    if (t < 32) idxs[t] = neighbors[(i << 5) + t];
    if (t == 0) { s_valid = 0xFFFFFFFFu; s_cntf = 0.f; s_done = 0; }
    __syncthreads();
    // ---- a1 = fi @ W1a + b1 ----
    if (t < 128) {
      float aa0 = b1s[t], aa1 = 0.0f;
      #pragma unroll 8
      for (int e = 0; e < 64; e += 2) {
        aa0 = fmaf(fis[e],     W1s[e * 128 + t],       aa0);
        aa1 = fmaf(fis[e + 1], W1s[(e + 1) * 128 + t], aa1);
      }
      a1s[t] = aa0 + aa1;
    }
    __syncthreads();

    for (int st = 0; st < 3; ++st) {
      // ---- B1: wave w produces rows {w+4n, n=0..7} plus row 32 (all waves,
      //      identical values -> benign concurrent same-value stores) ----
      {
        float2 av = *(const float2*)&a1s[lane << 1];
        #pragma unroll
        for (int n = 0; n < 8; ++n) {
          int k = wave + (n << 2);
          float hx = av.x, hy = av.y;
          int v = idxs[k];
          if (v > 0) {
            float2 yv = *(const float2*)&Yl[k][lane << 1];
            hx += yv.x; hy += yv.y;
          }
          hx = fmaxf(hx, 0.f); hy = fmaxf(hy, 0.f);
          float2 hw = {hx, hy};
          *(float2*)&h1s[k][lane << 1] = hw;
        }
        {
          float hx = fmaxf(av.x, 0.f), hy = fmaxf(av.y, 0.f);
          float2 hw = {hx, hy};
          *(float2*)&h1s[32][lane << 1] = hw;
        }
        // ---- B2: 9 rows share each W2 chunk read (8-9x reuse).
        //      acc chains: c = 0,1,2,3 mod 4 -> identical bits to prev kernel.
        f32x4 acc[9];
        #pragma unroll
        for (int n = 0; n < 9; ++n) acc[n] = (f32x4){b2s[lane], 0.f, 0.f, 0.f};
        #pragma unroll
        for (int m = 0; m < 32; ++m) {
          f32x4 wv = *(const f32x4*)&W2Ts[lane][(m << 2) ^ wsw];
          #pragma unroll
          for (int n = 0; n < 9; ++n) {
            int k = (n < 8) ? (wave + (n << 2)) : 32;
            f32x4 hv = *(const f32x4*)&h1s[k][m << 2];   // broadcast read
            acc[n] = __builtin_elementwise_fma(hv, wv, acc[n]);
          }
        }
        #pragma unroll
        for (int n = 0; n < 9; ++n) {
          int k = (n < 8) ? (wave + (n << 2)) : 32;
          float h2v = fmaxf((acc[n][0] + acc[n][1]) + (acc[n][2] + acc[n][3]), 0.f);
          h2s[k][lane] = h2v;
          float p = h2v * wlks[lane];
          #pragma unroll
          for (int off = 32; off; off >>= 1) p += __shfl_down(p, off);
          if (lane == 0) lks[k] = p + blkv;
        }
      }
      __syncthreads();
      // ---- P4+D fused (wave 0 only) ----
      if (wave == 0) {
        const unsigned vm = s_valid;
        const float cnt_old = s_cntf;
        const int done_old = s_done;
        float v = -__builtin_inff();
        int ki = 64;
        if (lane < 33) {
          bool m = (lane == 32) || ((vm >> lane) & 1u);
          v = m ? lks[lane] : -__builtin_inff();
          ki = lane;
        }
        #pragma unroll
        for (int off = 32; off; off >>= 1) {
          float ov = __shfl_down(v, off);
          int   oi = __shfl_down(ki, off);
          if (ov > v || (ov == v && oi < ki)) { v = ov; ki = oi; }
        }
        const int ut = __shfl(ki, 0);
        const int utc = ut < 31 ? ut : 31;
        float h = h2s[utc][lane];
        float p0 = h * wacts[(lane << 1) + 0];
        float p1 = h * wacts[(lane << 1) + 1];
        #pragma unroll
        for (int off = 32; off; off >>= 1) {
          p0 += __shfl_down(p0, off);
          p1 += __shfl_down(p1, off);
        }
        int at1 = 0;
        if (lane == 0) at1 = ((p1 + ba1) > (p0 + ba0)) ? 1 : 0;
        at1 = __shfl(at1, 0);
        const int newdone = done_old | (ut == 32);
        const int upd = newdone ? 0 : 1;
        const float take = at1 ? 1.0f : 0.0f;
        const float denom = cnt_old + take + 1.0f;
        const int u = idxs[utc];
        unsigned long long bu = __ballot(lane < 32 && idxs[lane] == u);
        unsigned long long bi = __ballot(lane < 32 && idxs[lane] == i);
        if (lane == 0) {
          s_u = u; s_upd = upd; s_utc = utc; s_done = newdone;
          s_mu = (unsigned)bu; s_mi = (unsigned)bi;
          if (upd) { s_valid = vm & ~(1u << utc); s_cntf = cnt_old + take; }
        }
        if (upd) {
          const float gu = G0l[utc][lane];
          const float ns = sumg[lane] + take * gu;
          const float hv = (ns + gis[lane]) / denom;
          const float nfi = fmaxf(hv + bembs[lane], 0.0f);
          sumg[lane] = ns;
          const float f0u = f0l[utc][lane];
          feature[i * 64 + lane] = nfi;            // feature[u] wins if u==i
          feature[u * 64 + lane] = f0u;
          fis[lane] = (u == i) ? f0u : nfi;
        }
      }
      __syncthreads();
      if (!s_upd) break;
      // ---- E: t<128 -> Y rows (+ Yl patches); t in [128,256) -> a1 ----
      {
        const int u = s_u;
        const int c = t & 127;
        if (t < 128) {
          const float yu = Y0[u * 128 + c];        // issued early, overlaps FMAs
          f32x2 acc = {0.f, 0.f};
          #pragma unroll 4
          for (int e = 0; e < 64; e += 2) {
            f32x2 fv = *(const f32x2*)&fis[e];
            f32x2 wv = {W1s[(64 + e) * 128 + c], W1s[(64 + e + 1) * 128 + c]};
            acc = __builtin_elementwise_fma(fv, wv, acc);
          }
          const float yi = acc[0] + acc[1];
          Y[i * 128 + c] = yi;                     // Y[u] wins if u==i
          Y[u * 128 + c] = yu;
          // patch LDS neighbor cache: slots holding u -> Y0[u]; slots holding i -> yi
          const unsigned mu = s_mu;
          for (unsigned m = mu; m; m &= m - 1) {
            int k = __ffs(m) - 1;
            Yl[k][c] = yu;
          }
          for (unsigned m = s_mi & ~mu; m; m &= m - 1) {
            int k = __ffs(m) - 1;
            Yl[k][c] = yi;
          }
        } else {
          f32x2 aa = {b1s[c], 0.f};
          #pragma unroll 4
          for (int e = 0; e < 64; e += 2) {
            f32x2 fv = *(const f32x2*)&fis[e];
            f32x2 wv = {W1s[e * 128 + c], W1s[(e + 1) * 128 + c]};
            aa = __builtin_elementwise_fma(fv, wv, aa);
          }
          a1s[c] = aa[0] + aa[1];
        }
      }
      __syncthreads();
    }
  }
}

// ---------------------------------------------------------------------------
extern "C" void kernel_launch(void* const* d_in, const int* in_sizes, int n_in,
                              void* d_out, int out_size, void* d_ws, size_t ws_size,
                              hipStream_t stream) {
  const float* X     = (const float*)d_in[0];
  const int*   nbr   = (const int*)  d_in[1];
  const float* W_emb = (const float*)d_in[2];
  const float* b_emb = (const float*)d_in[3];
  const float* W1    = (const float*)d_in[4];
  const float* b1    = (const float*)d_in[5];
  const float* W2    = (const float*)d_in[6];
  const float* b2    = (const float*)d_in[7];
  const float* W_lk  = (const float*)d_in[8];
  const float* b_lk  = (const float*)d_in[9];
  const float* W_act = (const float*)d_in[10];
  const float* b_act = (const float*)d_in[11];
  float* out = (float*)d_out;
  float* ws  = (float*)d_ws;
  float* G0    = ws;             // [1024*64]
  float* feat0 = ws + 65536;     // [1024*64]
  float* Y0    = ws + 131072;    // [1024*128]
  float* Y     = ws + 262144;    // [1024*128]

  hipLaunchKernelGGL(k_embed, dim3(256), dim3(256), 0, stream,
                     X, W_emb, b_emb, G0, feat0, out);
  hipLaunchKernelGGL(k_y0, dim3(1024), dim3(128), 0, stream,
                     feat0, W1, Y0, Y);
  hipLaunchKernelGGL(k_serial, dim3(1), dim3(256), 0, stream,
                     nbr, W1, b1, W2, b2, W_lk, b_lk, W_act, b_act, b_emb,
                     G0, feat0, Y0, Y, out);
}

// Round 5
// 21832.025 us; speedup vs baseline: 6.5981x; 6.5981x over previous
//
#include <hip/hip_runtime.h>

// Problem constants: N=1024, K=32, F=8192, E=64, H1=128, H2=64, T=3

typedef float f32x4 __attribute__((ext_vector_type(4)));
typedef float f32x2 __attribute__((ext_vector_type(2)));

// ---------------------------------------------------------------------------
// K1: G0 = X @ W_emb (f64 accumulation), feat0 = relu(G0 + b_emb), out=feat0
// ---------------------------------------------------------------------------
__global__ __launch_bounds__(256) void k_embed(
    const float* __restrict__ X, const float* __restrict__ W_emb,
    const float* __restrict__ b_emb,
    float* __restrict__ G0, float* __restrict__ feat0, float* __restrict__ out)
{
  const int t = threadIdx.x;
  const int j = t & 63;
  const int node = (blockIdx.x << 2) + (t >> 6);
  const float* __restrict__ xr = X + (size_t)node * 8192;
  const float* __restrict__ wp = W_emb + j;
  double a0 = 0.0, a1 = 0.0, a2 = 0.0, a3 = 0.0;
  for (int f = 0; f < 8192; f += 4) {
    float x0 = xr[f + 0], x1 = xr[f + 1], x2 = xr[f + 2], x3 = xr[f + 3];
    a0 = fma((double)x0, (double)wp[(f + 0) << 6], a0);
    a1 = fma((double)x1, (double)wp[(f + 1) << 6], a1);
    a2 = fma((double)x2, (double)wp[(f + 2) << 6], a2);
    a3 = fma((double)x3, (double)wp[(f + 3) << 6], a3);
  }
  float g = (float)((a0 + a1) + (a2 + a3));
  const int o = node * 64 + j;
  G0[o] = g;
  float f0 = fmaxf(g + b_emb[j], 0.0f);
  feat0[o] = f0;
  out[o] = f0;
}

// ---------------------------------------------------------------------------
// K2: Y0 = feat0 @ W1b (W1 rows 64..127); Y = Y0 working copy
// ---------------------------------------------------------------------------
__global__ __launch_bounds__(128) void k_y0(
    const float* __restrict__ feat0, const float* __restrict__ W1,
    float* __restrict__ Y0, float* __restrict__ Y)
{
  const int c = threadIdx.x;
  const int i = blockIdx.x;
  const float* __restrict__ fr = feat0 + i * 64;
  float acc = 0.0f;
  #pragma unroll 8
  for (int e = 0; e < 64; ++e)
    acc = fmaf(fr[e], W1[(64 + e) * 128 + c], acc);
  Y0[i * 128 + c] = acc;
  Y[i * 128 + c] = acc;
}

// ---------------------------------------------------------------------------
// K3: serial chain. 512 threads / 8 waves. W2 transposed in LDS with +4-dword
// row padding (stride 132) -> lane j's b128 read of chunk m starts at bank
// 4*((j+m)&7): uniform 8 lanes per 4-bank group = conflict-free floor.
// Wave w owns h1/h2 rows {w+8n, n=0..3} -> acc[4] only (no spill).
// Row 32 contributes only lks[32]; wave 0 computes it from relu(a1) directly.
// All FMA chain orders bit-identical to passing rounds -> same decisions.
// ---------------------------------------------------------------------------
__global__ __launch_bounds__(512, 2) void k_serial(
    const int* __restrict__ neighbors,
    const float* __restrict__ W1, const float* __restrict__ b1,
    const float* __restrict__ W2, const float* __restrict__ b2,
    const float* __restrict__ W_lk, const float* __restrict__ b_lk,
    const float* __restrict__ W_act, const float* __restrict__ b_act,
    const float* __restrict__ b_emb,
    const float* __restrict__ G0, const float* __restrict__ feat0,
    const float* __restrict__ Y0, float* __restrict__ Y,
    float* __restrict__ feature)   // == d_out
{
  __shared__ __align__(16) float W1s[128 * 128];   // 64 KB
  __shared__ __align__(16) float W2Ts[64 * 132];   // 33 KB, padded transpose
  __shared__ __align__(16) float Yl[32][128];      // 16 KB
  __shared__ __align__(16) float G0l[32][64];      // 8 KB
  __shared__ __align__(16) float f0l[32][64];      // 8 KB
  __shared__ __align__(16) float h1s[32][128];     // 16 KB
  __shared__ __align__(16) float h2s[32][64];      // 8 KB
  __shared__ __align__(16) float a1s[128];
  __shared__ __align__(16) float fis[64];
  __shared__ float gis[64], sumg[64];
  __shared__ float b1s[128], b2s[64], bembs[64], wlks[64], wacts[128];
  __shared__ float lks[33];
  __shared__ int idxs[32];
  __shared__ int s_u, s_upd, s_utc, s_done;
  __shared__ unsigned s_valid, s_mu, s_mi;
  __shared__ float s_cntf;

  const int t = threadIdx.x;
  const int lane = t & 63;
  const int wave = t >> 6;
  const int w2base = lane * 132;

  // ---- one-time staging ----
  #pragma unroll
  for (int m = 0; m < 8; ++m) {
    int i4 = (m * 512 + t) << 2;
    *(float4*)&W1s[i4] = *(const float4*)&W1[i4];
  }
  // W2Ts[j*132 + c] = W2[c*64 + j]
  for (int e = t; e < 8192; e += 512) {
    int c = e >> 6, j = e & 63;
    W2Ts[j * 132 + c] = W2[e];
  }
  if (t < 128) { b1s[t] = b1[t]; wacts[t] = W_act[t]; }
  if (t < 64) { b2s[t] = b2[t]; bembs[t] = b_emb[t]; wlks[t] = W_lk[t]; }
  const float blkv = b_lk[0];
  const float ba0 = b_act[0];
  const float ba1 = b_act[1];
  __syncthreads();

  for (int i = 0; i < 1024; ++i) {
    // ---- phase0: per-node prefetch into LDS ----
    #pragma unroll
    for (int p = 0; p < 2; ++p) {
      int fi = (p << 9) + t;               // 0..1023
      int k = fi >> 5;
      int c4 = (fi & 31) << 2;
      int v = neighbors[(i << 5) + k];
      *(float4*)&Yl[k][c4] = *(const float4*)&Y[v * 128 + c4];
    }
    {
      int k = t >> 4;                      // 0..31
      int c4 = (t & 15) << 2;
      int v = neighbors[(i << 5) + k];
      *(float4*)&G0l[k][c4] = *(const float4*)&G0[v * 64 + c4];
      *(float4*)&f0l[k][c4] = *(const float4*)&feat0[v * 64 + c4];
    }
    if (t < 64) { fis[t] = feature[i * 64 + t]; gis[t] = G0[i * 64 + t]; sumg[t] = 0.f; }
    if (t < 32) idxs[t] = neighbors[(i << 5) + t];
    if (t == 0) { s_valid = 0xFFFFFFFFu; s_cntf = 0.f; s_done = 0; }
    __syncthreads();
    // ---- a1 = fi @ W1a + b1 ----
    if (t < 128) {
      float aa0 = b1s[t], aa1 = 0.0f;
      #pragma unroll 8
      for (int e = 0; e < 64; e += 2) {
        aa0 = fmaf(fis[e],     W1s[e * 128 + t],       aa0);
        aa1 = fmaf(fis[e + 1], W1s[(e + 1) * 128 + t], aa1);
      }
      a1s[t] = aa0 + aa1;
    }
    __syncthreads();

    for (int st = 0; st < 3; ++st) {
      // ---- B1: wave w writes rows {w+8n}; no barrier before B2 (own rows) --
      {
        float2 av = *(const float2*)&a1s[lane << 1];
        #pragma unroll
        for (int n = 0; n < 4; ++n) {
          int k = wave + (n << 3);
          float hx = av.x, hy = av.y;
          int v = idxs[k];
          if (v > 0) {
            float2 yv = *(const float2*)&Yl[k][lane << 1];
            hx += yv.x; hy += yv.y;
          }
          hx = fmaxf(hx, 0.f); hy = fmaxf(hy, 0.f);
          float2 hw = {hx, hy};
          *(float2*)&h1s[k][lane << 1] = hw;
        }
      }
      // ---- B2 main: 4 rows share each W2 chunk read ----
      {
        f32x4 acc0 = {b2s[lane], 0.f, 0.f, 0.f};
        f32x4 acc1 = acc0, acc2 = acc0, acc3 = acc0;
        #pragma unroll 4
        for (int m = 0; m < 32; ++m) {
          f32x4 wv = *(const f32x4*)&W2Ts[w2base + (m << 2)];
          f32x4 h0 = *(const f32x4*)&h1s[wave     ][m << 2];
          f32x4 h1v = *(const f32x4*)&h1s[wave + 8][m << 2];
          f32x4 h2v = *(const f32x4*)&h1s[wave + 16][m << 2];
          f32x4 h3v = *(const f32x4*)&h1s[wave + 24][m << 2];
          acc0 = __builtin_elementwise_fma(h0,  wv, acc0);
          acc1 = __builtin_elementwise_fma(h1v, wv, acc1);
          acc2 = __builtin_elementwise_fma(h2v, wv, acc2);
          acc3 = __builtin_elementwise_fma(h3v, wv, acc3);
        }
        f32x4 accs[4] = {acc0, acc1, acc2, acc3};
        #pragma unroll
        for (int n = 0; n < 4; ++n) {
          int k = wave + (n << 3);
          float h2v = fmaxf((accs[n][0] + accs[n][1]) + (accs[n][2] + accs[n][3]), 0.f);
          h2s[k][lane] = h2v;
          float p = h2v * wlks[lane];
          #pragma unroll
          for (int off = 32; off; off >>= 1) p += __shfl_down(p, off);
          if (lane == 0) lks[k] = p + blkv;
        }
      }
      // ---- B2 ending-row (k=32): wave 0 only; h1 = relu(a1) on the fly ----
      if (wave == 0) {
        f32x4 acc = {b2s[lane], 0.f, 0.f, 0.f};
        #pragma unroll 4
        for (int m = 0; m < 32; ++m) {
          f32x4 wv = *(const f32x4*)&W2Ts[w2base + (m << 2)];
          f32x4 av = *(const f32x4*)&a1s[m << 2];
          f32x4 hv;
          hv[0] = fmaxf(av[0], 0.f); hv[1] = fmaxf(av[1], 0.f);
          hv[2] = fmaxf(av[2], 0.f); hv[3] = fmaxf(av[3], 0.f);
          acc = __builtin_elementwise_fma(hv, wv, acc);
        }
        float h2v = fmaxf((acc[0] + acc[1]) + (acc[2] + acc[3]), 0.f);
        float p = h2v * wlks[lane];
        #pragma unroll
        for (int off = 32; off; off >>= 1) p += __shfl_down(p, off);
        if (lane == 0) lks[32] = p + blkv;
      }
      __syncthreads();
      // ---- P4+D fused (wave 0 only) ----
      if (wave == 0) {
        const unsigned vm = s_valid;
        const float cnt_old = s_cntf;
        const int done_old = s_done;
        float v = -__builtin_inff();
        int ki = 64;
        if (lane < 33) {
          bool m = (lane == 32) || ((vm >> lane) & 1u);
          v = m ? lks[lane] : -__builtin_inff();
          ki = lane;
        }
        #pragma unroll
        for (int off = 32; off; off >>= 1) {
          float ov = __shfl_down(v, off);
          int   oi = __shfl_down(ki, off);
          if (ov > v || (ov == v && oi < ki)) { v = ov; ki = oi; }
        }
        const int ut = __shfl(ki, 0);
        const int utc = ut < 31 ? ut : 31;
        float h = h2s[utc][lane];
        float p0 = h * wacts[(lane << 1) + 0];
        float p1 = h * wacts[(lane << 1) + 1];
        #pragma unroll
        for (int off = 32; off; off >>= 1) {
          p0 += __shfl_down(p0, off);
          p1 += __shfl_down(p1, off);
        }
        int at1 = 0;
        if (lane == 0) at1 = ((p1 + ba1) > (p0 + ba0)) ? 1 : 0;
        at1 = __shfl(at1, 0);
        const int newdone = done_old | (ut == 32);
        const int upd = newdone ? 0 : 1;
        const float take = at1 ? 1.0f : 0.0f;
        const float denom = cnt_old + take + 1.0f;
        const int u = idxs[utc];
        unsigned long long bu = __ballot(lane < 32 && idxs[lane] == u);
        unsigned long long bi = __ballot(lane < 32 && idxs[lane] == i);
        if (lane == 0) {
          s_u = u; s_upd = upd; s_utc = utc; s_done = newdone;
          s_mu = (unsigned)bu; s_mi = (unsigned)bi;
          if (upd) { s_valid = vm & ~(1u << utc); s_cntf = cnt_old + take; }
        }
        if (upd) {
          const float gu = G0l[utc][lane];
          const float ns = sumg[lane] + take * gu;
          const float hv = (ns + gis[lane]) / denom;
          const float nfi = fmaxf(hv + bembs[lane], 0.0f);
          sumg[lane] = ns;
          const float f0u = f0l[utc][lane];
          feature[i * 64 + lane] = nfi;            // feature[u] wins if u==i
          feature[u * 64 + lane] = f0u;
          fis[lane] = (u == i) ? f0u : nfi;
        }
      }
      __syncthreads();
      if (!s_upd) break;
      // ---- E: t<128 -> Y rows (+ Yl patches); t in [128,256) -> a1 ----
      {
        const int u = s_u;
        const int c = t & 127;
        if (t < 128) {
          const float yu = Y0[u * 128 + c];        // early issue, overlaps FMAs
          f32x2 acc = {0.f, 0.f};
          #pragma unroll 4
          for (int e = 0; e < 64; e += 2) {
            f32x2 fv = *(const f32x2*)&fis[e];
            f32x2 wv = {W1s[(64 + e) * 128 + c], W1s[(64 + e + 1) * 128 + c]};
            acc = __builtin_elementwise_fma(fv, wv, acc);
          }
          const float yi = acc[0] + acc[1];
          Y[i * 128 + c] = yi;                     // Y[u] wins if u==i
          Y[u * 128 + c] = yu;
          const unsigned mu = s_mu;
          for (unsigned m = mu; m; m &= m - 1) {
            int k = __ffs(m) - 1;
            Yl[k][c] = yu;
          }
          for (unsigned m = s_mi & ~mu; m; m &= m - 1) {
            int k = __ffs(m) - 1;
            Yl[k][c] = yi;
          }
        } else if (t < 256) {
          f32x2 aa = {b1s[c], 0.f};
          #pragma unroll 4
          for (int e = 0; e < 64; e += 2) {
            f32x2 fv = *(const f32x2*)&fis[e];
            f32x2 wv = {W1s[e * 128 + c], W1s[(e + 1) * 128 + c]};
            aa = __builtin_elementwise_fma(fv, wv, aa);
          }
          a1s[c] = aa[0] + aa[1];
        }
      }
      __syncthreads();
    }
  }
}

// ---------------------------------------------------------------------------
extern "C" void kernel_launch(void* const* d_in, const int* in_sizes, int n_in,
                              void* d_out, int out_size, void* d_ws, size_t ws_size,
                              hipStream_t stream) {
  const float* X     = (const float*)d_in[0];
  const int*   nbr   = (const int*)  d_in[1];
  const float* W_emb = (const float*)d_in[2];
  const float* b_emb = (const float*)d_in[3];
  const float* W1    = (const float*)d_in[4];
  const float* b1    = (const float*)d_in[5];
  const float* W2    = (const float*)d_in[6];
  const float* b2    = (const float*)d_in[7];
  const float* W_lk  = (const float*)d_in[8];
  const float* b_lk  = (const float*)d_in[9];
  const float* W_act = (const float*)d_in[10];
  const float* b_act = (const float*)d_in[11];
  float* out = (float*)d_out;
  float* ws  = (float*)d_ws;
  float* G0    = ws;             // [1024*64]
  float* feat0 = ws + 65536;     // [1024*64]
  float* Y0    = ws + 131072;    // [1024*128]
  float* Y     = ws + 262144;    // [1024*128]

  hipLaunchKernelGGL(k_embed, dim3(256), dim3(256), 0, stream,
                     X, W_emb, b_emb, G0, feat0, out);
  hipLaunchKernelGGL(k_y0, dim3(1024), dim3(128), 0, stream,
                     feat0, W1, Y0, Y);
  hipLaunchKernelGGL(k_serial, dim3(1), dim3(512), 0, stream,
                     nbr, W1, b1, W2, b2, W_lk, b_lk, W_act, b_act, b_emb,
                     G0, feat0, Y0, Y, out);
}

// Round 7
// 12425.117 us; speedup vs baseline: 11.5935x; 1.7571x over previous
//
#include <hip/hip_runtime.h>

// Problem constants: N=1024, K=32, F=8192, E=64, H1=128, H2=64, T=3

typedef float f32x4 __attribute__((ext_vector_type(4)));
typedef float f32x2 __attribute__((ext_vector_type(2)));
typedef short bf16x8 __attribute__((ext_vector_type(8)));

__device__ __forceinline__ unsigned short bf16_rne(float x) {
  unsigned u = __builtin_bit_cast(unsigned, x);
  unsigned r = (u + 0x7FFFu + ((u >> 16) & 1u)) >> 16;
  return (unsigned short)r;
}
__device__ __forceinline__ float bf16_f(unsigned short h) {
  return __builtin_bit_cast(float, ((unsigned)h) << 16);
}
__device__ __forceinline__ void split3(float x, unsigned short& h, unsigned short& m,
                                       unsigned short& l) {
  h = bf16_rne(x); float r  = x - bf16_f(h);
  m = bf16_rne(r); float r2 = r - bf16_f(m);
  l = bf16_rne(r2);
}

// ---------------------------------------------------------------------------
// K1: G0 = X @ W_emb (f64 accumulation), feat0 = relu(G0 + b_emb), out=feat0
// ---------------------------------------------------------------------------
__global__ __launch_bounds__(256) void k_embed(
    const float* __restrict__ X, const float* __restrict__ W_emb,
    const float* __restrict__ b_emb,
    float* __restrict__ G0, float* __restrict__ feat0, float* __restrict__ out)
{
  const int t = threadIdx.x;
  const int j = t & 63;
  const int node = (blockIdx.x << 2) + (t >> 6);
  const float* __restrict__ xr = X + (size_t)node * 8192;
  const float* __restrict__ wp = W_emb + j;
  double a0 = 0.0, a1 = 0.0, a2 = 0.0, a3 = 0.0;
  for (int f = 0; f < 8192; f += 4) {
    float x0 = xr[f + 0], x1 = xr[f + 1], x2 = xr[f + 2], x3 = xr[f + 3];
    a0 = fma((double)x0, (double)wp[(f + 0) << 6], a0);
    a1 = fma((double)x1, (double)wp[(f + 1) << 6], a1);
    a2 = fma((double)x2, (double)wp[(f + 2) << 6], a2);
    a3 = fma((double)x3, (double)wp[(f + 3) << 6], a3);
  }
  float g = (float)((a0 + a1) + (a2 + a3));
  const int o = node * 64 + j;
  G0[o] = g;
  float f0 = fmaxf(g + b_emb[j], 0.0f);
  feat0[o] = f0;
  out[o] = f0;
}

// ---------------------------------------------------------------------------
// K2: Y0 = feat0 @ W1b (W1 rows 64..127); Y = Y0 working copy
// ---------------------------------------------------------------------------
__global__ __launch_bounds__(128) void k_y0(
    const float* __restrict__ feat0, const float* __restrict__ W1,
    float* __restrict__ Y0, float* __restrict__ Y)
{
  const int c = threadIdx.x;
  const int i = blockIdx.x;
  const float* __restrict__ fr = feat0 + i * 64;
  float acc = 0.0f;
  #pragma unroll 8
  for (int e = 0; e < 64; ++e)
    acc = fmaf(fr[e], W1[(64 + e) * 128 + c], acc);
  Y0[i * 128 + c] = acc;
  Y[i * 128 + c] = acc;
}

// ---------------------------------------------------------------------------
// K3: serial chain, 512 threads / 8 waves.
// B2 = MFMA: C' = W2^T (A-operand, split-3 bf16 frags in VGPRs, loaded once)
//            x h1^T (B-operand, split-3 bf16 planes in LDS, XOR-swizzled).
// Swizzle: write uintpos = lane ^ ((row&7)<<2)  <->  read group
//          g' = ((kc<<2)+lg) ^ (row&7)   (XOR on the full 8-ushort-group idx;
//          round-6 bug was XORing lg only and ADDING into the kc field).
// C' layout: col(lane&15) = h1-row, row(4*(lane>>4)+reg) = W2-col ->
// lk/at partial dots are lane-local (3 FMAs) + 2 shfl_xor.
// State-update chains (a1/D/E) bit-identical to prior passing rounds.
// ---------------------------------------------------------------------------
__global__ __launch_bounds__(512, 2) void k_serial(
    const int* __restrict__ neighbors,
    const float* __restrict__ W1, const float* __restrict__ b1,
    const float* __restrict__ W2, const float* __restrict__ b2,
    const float* __restrict__ W_lk, const float* __restrict__ b_lk,
    const float* __restrict__ W_act, const float* __restrict__ b_act,
    const float* __restrict__ b_emb,
    const float* __restrict__ G0, const float* __restrict__ feat0,
    const float* __restrict__ Y0, float* __restrict__ Y,
    float* __restrict__ feature)   // == d_out
{
  __shared__ __align__(16) float W1s[128 * 128];            // 64 KB
  __shared__ __align__(16) unsigned short Ash[48 * 128];    // 12 KB  h1 hi plane
  __shared__ __align__(16) unsigned short Asm[48 * 128];    // 12 KB  h1 mid plane
  __shared__ __align__(16) unsigned short Asl[48 * 128];    // 12 KB  h1 lo plane
  __shared__ __align__(16) float Yl[32][128];               // 16 KB
  __shared__ __align__(16) float G0l[32][64];               // 8 KB
  __shared__ __align__(16) float f0l[32][64];               // 8 KB
  __shared__ __align__(16) float a1s[128];
  __shared__ __align__(16) float fis[64];
  __shared__ float gis[64], sumg[64];
  __shared__ __align__(16) float b1s[128], b2s[64], bembs[64], wlks[64], wacts[128];
  __shared__ float lkps[4][48], p0s[4][48], p1s[4][48];
  __shared__ int idxs[32];
  __shared__ int s_u, s_upd, s_utc, s_done;
  __shared__ unsigned s_valid, s_mu, s_mi;
  __shared__ float s_cntf;

  const int t = threadIdx.x;
  const int lane = t & 63;
  const int wave = t >> 6;
  const int l15 = lane & 15;
  const int lg = lane >> 4;            // 0..3
  const int mt = wave & 3;             // W2-col tile of this wave
  const int m0 = mt << 4;

  // ---- one-time staging ----
  #pragma unroll
  for (int m = 0; m < 8; ++m) {
    int i4 = (m * 512 + t) << 2;
    *(float4*)&W1s[i4] = *(const float4*)&W1[i4];
  }
  if (t < 128) { b1s[t] = b1[t]; wacts[t] = W_act[t]; }
  if (t < 64) { b2s[t] = b2[t]; bembs[t] = b_emb[t]; wlks[t] = W_lk[t]; }
  // zero A-plane pad rows 33..47 (uint granularity; swizzle is row-bijective)
  for (int idx = 33 * 64 + t; idx < 48 * 64; idx += 512) {
    ((unsigned*)Ash)[idx] = 0u;
    ((unsigned*)Asm)[idx] = 0u;
    ((unsigned*)Asl)[idx] = 0u;
  }
  const float blkv = b_lk[0];
  const float ba0 = b_act[0];
  const float ba1 = b_act[1];
  // W2^T A-frags, split-3, in VGPRs (once). col = m0+l15, k = 32kc + 8lg + e.
  bf16x8 wh[4], wm[4], wl[4];
  #pragma unroll
  for (int kc = 0; kc < 4; ++kc) {
    bf16x8 vh, vm, vl;
    #pragma unroll
    for (int e = 0; e < 8; ++e) {
      int k = (kc << 5) + (lg << 3) + e;
      float x = W2[k * 64 + m0 + l15];
      unsigned short sh, sm, sl;
      split3(x, sh, sm, sl);
      vh[e] = (short)sh; vm[e] = (short)sm; vl[e] = (short)sl;
    }
    wh[kc] = vh; wm[kc] = vm; wl[kc] = vl;
  }
  __syncthreads();

  for (int i = 0; i < 1024; ++i) {
    // ---- phase0: per-node prefetch into LDS ----
    #pragma unroll
    for (int p = 0; p < 2; ++p) {
      int fi = (p << 9) + t;               // 0..1023
      int k = fi >> 5;
      int c4 = (fi & 31) << 2;
      int v = neighbors[(i << 5) + k];
      *(float4*)&Yl[k][c4] = *(const float4*)&Y[v * 128 + c4];
    }
    {
      int k = t >> 4;                      // 0..31
      int c4 = (t & 15) << 2;
      int v = neighbors[(i << 5) + k];
      *(float4*)&G0l[k][c4] = *(const float4*)&G0[v * 64 + c4];
      *(float4*)&f0l[k][c4] = *(const float4*)&feat0[v * 64 + c4];
    }
    if (t < 64) { fis[t] = feature[i * 64 + t]; gis[t] = G0[i * 64 + t]; sumg[t] = 0.f; }
    if (t < 32) idxs[t] = neighbors[(i << 5) + t];
    if (t == 0) { s_valid = 0xFFFFFFFFu; s_cntf = 0.f; s_done = 0; }
    __syncthreads();
    // ---- a1 = fi @ W1a + b1 (exact chain) ----
    if (t < 128) {
      float aa0 = b1s[t], aa1 = 0.0f;
      #pragma unroll 8
      for (int e = 0; e < 64; e += 2) {
        aa0 = fmaf(fis[e],     W1s[e * 128 + t],       aa0);
        aa1 = fmaf(fis[e + 1], W1s[(e + 1) * 128 + t], aa1);
      }
      a1s[t] = aa0 + aa1;
    }
    __syncthreads();

    for (int st = 0; st < 3; ++st) {
      // ---- B1: exact f32 h1, split-3 into A-planes (XOR-swizzled) ----
      {
        float2 av = *(const float2*)&a1s[lane << 1];
        #pragma unroll
        for (int n = 0; n < 4; ++n) {
          int k = wave + (n << 3);
          float hx = av.x, hy = av.y;
          int v = idxs[k];
          if (v > 0) {
            float2 yv = *(const float2*)&Yl[k][lane << 1];
            hx += yv.x; hy += yv.y;
          }
          hx = fmaxf(hx, 0.f); hy = fmaxf(hy, 0.f);
          unsigned short xh, xm, xl, yh, ym, yl2;
          split3(hx, xh, xm, xl);
          split3(hy, yh, ym, yl2);
          unsigned base = (k << 6) + (lane ^ ((k & 7) << 2));   // uint index
          ((unsigned*)Ash)[base] = (unsigned)xh | ((unsigned)yh << 16);
          ((unsigned*)Asm)[base] = (unsigned)xm | ((unsigned)ym << 16);
          ((unsigned*)Asl)[base] = (unsigned)xl | ((unsigned)yl2 << 16);
        }
        if (wave == 4) {   // ending row 32: h1 = relu(a1)
          const int k = 32;
          float hx = fmaxf(av.x, 0.f), hy = fmaxf(av.y, 0.f);
          unsigned short xh, xm, xl, yh, ym, yl2;
          split3(hx, xh, xm, xl);
          split3(hy, yh, ym, yl2);
          unsigned base = (k << 6) + (lane ^ ((k & 7) << 2));
          ((unsigned*)Ash)[base] = (unsigned)xh | ((unsigned)yh << 16);
          ((unsigned*)Asm)[base] = (unsigned)xm | ((unsigned)ym << 16);
          ((unsigned*)Asl)[base] = (unsigned)xl | ((unsigned)yl2 << 16);
        }
      }
      __syncthreads();
      // ---- B2: MFMA tiles. waves 0-3: nt {0,2}; waves 4-7: nt {1} ----
      {
        #pragma unroll
        for (int tt = 0; tt < 2; ++tt) {
          int nt = (wave < 4) ? ((tt == 0) ? 0 : 2) : 1;
          bool active = (wave < 4) || (tt == 0);
          if (active) {
            const int n0 = nt << 4;
            const int row = n0 + l15;
            f32x4 c = *(const f32x4*)&b2s[m0 + (lg << 2)];
            #pragma unroll
            for (int kc = 0; kc < 4; ++kc) {
              // group idx g = (kc<<2)+lg; swizzled group = g ^ (row&7)
              const int ao = (row << 7) + ((((kc << 2) + lg) ^ (row & 7)) << 3);
              bf16x8 ah = *(const bf16x8*)&Ash[ao];
              bf16x8 am = *(const bf16x8*)&Asm[ao];
              bf16x8 al = *(const bf16x8*)&Asl[ao];
              c = __builtin_amdgcn_mfma_f32_16x16x32_bf16(wh[kc], ah, c, 0, 0, 0);
              c = __builtin_amdgcn_mfma_f32_16x16x32_bf16(wh[kc], am, c, 0, 0, 0);
              c = __builtin_amdgcn_mfma_f32_16x16x32_bf16(wm[kc], ah, c, 0, 0, 0);
              c = __builtin_amdgcn_mfma_f32_16x16x32_bf16(wh[kc], al, c, 0, 0, 0);
              c = __builtin_amdgcn_mfma_f32_16x16x32_bf16(wl[kc], ah, c, 0, 0, 0);
              c = __builtin_amdgcn_mfma_f32_16x16x32_bf16(wm[kc], am, c, 0, 0, 0);
            }
            // epilogue: lane -> h1-row (n0+l15), W2-cols m0+4lg..+3
            f32x4 wl4 = *(const f32x4*)&wlks[m0 + (lg << 2)];
            f32x4 wa_a = *(const f32x4*)&wacts[(m0 + (lg << 2)) << 1];
            f32x4 wa_b = *(const f32x4*)&wacts[((m0 + (lg << 2)) << 1) + 4];
            float pl = 0.f, q0 = 0.f, q1 = 0.f;
            #pragma unroll
            for (int r = 0; r < 4; ++r) {
              float v = fmaxf(c[r], 0.f);
              float wa0v = (r < 2) ? wa_a[r << 1] : wa_b[(r - 2) << 1];
              float wa1v = (r < 2) ? wa_a[(r << 1) + 1] : wa_b[((r - 2) << 1) + 1];
              pl = fmaf(v, wl4[r], pl);
              q0 = fmaf(v, wa0v, q0);
              q1 = fmaf(v, wa1v, q1);
            }
            pl += __shfl_xor(pl, 16); pl += __shfl_xor(pl, 32);
            q0 += __shfl_xor(q0, 16); q0 += __shfl_xor(q0, 32);
            q1 += __shfl_xor(q1, 16); q1 += __shfl_xor(q1, 32);
            if (lg == 0) {
              lkps[mt][n0 + l15] = pl;
              p0s[mt][n0 + l15] = q0;
              p1s[mt][n0 + l15] = q1;
            }
          }
        }
      }
      __syncthreads();
      // ---- P4 + D (wave 0 only) ----
      if (wave == 0) {
        const unsigned vm = s_valid;
        const float cnt_old = s_cntf;
        const int done_old = s_done;
        float v = -__builtin_inff();
        int ki = 64;
        if (lane < 33) {
          bool msk = (lane == 32) || ((vm >> lane) & 1u);
          float lkv = ((lkps[0][lane] + lkps[1][lane]) +
                       (lkps[2][lane] + lkps[3][lane])) + blkv;
          v = msk ? lkv : -__builtin_inff();
          ki = lane;
        }
        #pragma unroll
        for (int off = 32; off; off >>= 1) {
          float ov = __shfl_down(v, off);
          int   oi = __shfl_down(ki, off);
          if (ov > v || (ov == v && oi < ki)) { v = ov; ki = oi; }
        }
        const int ut = __shfl(ki, 0);
        const int utc = ut < 31 ? ut : 31;
        int at1 = 0;
        if (lane == 0) {
          float d0 = ((p0s[0][utc] + p0s[1][utc]) +
                      (p0s[2][utc] + p0s[3][utc])) + ba0;
          float d1 = ((p1s[0][utc] + p1s[1][utc]) +
                      (p1s[2][utc] + p1s[3][utc])) + ba1;
          at1 = (d1 > d0) ? 1 : 0;
        }
        at1 = __shfl(at1, 0);
        const int newdone = done_old | (ut == 32);
        const int upd = newdone ? 0 : 1;
        const float take = at1 ? 1.0f : 0.0f;
        const float denom = cnt_old + take + 1.0f;
        const int u = idxs[utc];
        unsigned long long bu = __ballot(lane < 32 && idxs[lane] == u);
        unsigned long long bi = __ballot(lane < 32 && idxs[lane] == i);
        if (lane == 0) {
          s_u = u; s_upd = upd; s_utc = utc; s_done = newdone;
          s_mu = (unsigned)bu; s_mi = (unsigned)bi;
          if (upd) { s_valid = vm & ~(1u << utc); s_cntf = cnt_old + take; }
        }
        if (upd) {
          const float gu = G0l[utc][lane];
          const float ns = sumg[lane] + take * gu;
          const float hv = (ns + gis[lane]) / denom;
          const float nfi = fmaxf(hv + bembs[lane], 0.0f);
          sumg[lane] = ns;
          const float f0u = f0l[utc][lane];
          feature[i * 64 + lane] = nfi;            // feature[u] wins if u==i
          feature[u * 64 + lane] = f0u;
          fis[lane] = (u == i) ? f0u : nfi;
        }
      }
      __syncthreads();
      if (!s_upd) break;
      // ---- E: t<128 -> Y rows (+ Yl patches); t in [128,256) -> a1 ----
      {
        const int u = s_u;
        const int c = t & 127;
        if (t < 128) {
          const float yu = Y0[u * 128 + c];        // early issue, overlaps FMAs
          f32x2 acc = {0.f, 0.f};
          #pragma unroll 4
          for (int e = 0; e < 64; e += 2) {
            f32x2 fv = *(const f32x2*)&fis[e];
            f32x2 wv = {W1s[(64 + e) * 128 + c], W1s[(64 + e + 1) * 128 + c]};
            acc = __builtin_elementwise_fma(fv, wv, acc);
          }
          const float yi = acc[0] + acc[1];
          Y[i * 128 + c] = yi;                     // Y[u] wins if u==i
          Y[u * 128 + c] = yu;
          const unsigned mu = s_mu;
          for (unsigned m = mu; m; m &= m - 1) {
            int k = __ffs(m) - 1;
            Yl[k][c] = yu;
          }
          for (unsigned m = s_mi & ~mu; m; m &= m - 1) {
            int k = __ffs(m) - 1;
            Yl[k][c] = yi;
          }
        } else if (t < 256) {
          f32x2 aa = {b1s[c], 0.f};
          #pragma unroll 4
          for (int e = 0; e < 64; e += 2) {
            f32x2 fv = *(const f32x2*)&fis[e];
            f32x2 wv = {W1s[e * 128 + c], W1s[(e + 1) * 128 + c]};
            aa = __builtin_elementwise_fma(fv, wv, aa);
          }
          a1s[c] = aa[0] + aa[1];
        }
      }
      __syncthreads();
    }
  }
}

// ---------------------------------------------------------------------------
extern "C" void kernel_launch(void* const* d_in, const int* in_sizes, int n_in,
                              void* d_out, int out_size, void* d_ws, size_t ws_size,
                              hipStream_t stream) {
  const float* X     = (const float*)d_in[0];
  const int*   nbr   = (const int*)  d_in[1];
  const float* W_emb = (const float*)d_in[2];
  const float* b_emb = (const float*)d_in[3];
  const float* W1    = (const float*)d_in[4];
  const float* b1    = (const float*)d_in[5];
  const float* W2    = (const float*)d_in[6];
  const float* b2    = (const float*)d_in[7];
  const float* W_lk  = (const float*)d_in[8];
  const float* b_lk  = (const float*)d_in[9];
  const float* W_act = (const float*)d_in[10];
  const float* b_act = (const float*)d_in[11];
  float* out = (float*)d_out;
  float* ws  = (float*)d_ws;
  float* G0    = ws;             // [1024*64]
  float* feat0 = ws + 65536;     // [1024*64]
  float* Y0    = ws + 131072;    // [1024*128]
  float* Y     = ws + 262144;    // [1024*128]

  hipLaunchKernelGGL(k_embed, dim3(256), dim3(256), 0, stream,
                     X, W_emb, b_emb, G0, feat0, out);
  hipLaunchKernelGGL(k_y0, dim3(1024), dim3(128), 0, stream,
                     feat0, W1, Y0, Y);
  hipLaunchKernelGGL(k_serial, dim3(1), dim3(512), 0, stream,
                     nbr, W1, b1, W2, b2, W_lk, b_lk, W_act, b_act, b_emb,
                     G0, feat0, Y0, Y, out);
}

// Round 10
// 9631.141 us; speedup vs baseline: 14.9567x; 1.2901x over previous
//
#include <hip/hip_runtime.h>

// Problem constants: N=1024, K=32, F=8192, E=64, H1=128, H2=64, T=3

typedef float f32x4 __attribute__((ext_vector_type(4)));
typedef float f32x2 __attribute__((ext_vector_type(2)));
typedef short bf16x8 __attribute__((ext_vector_type(8)));

__device__ __forceinline__ unsigned short bf16_rne(float x) {
  unsigned u = __builtin_bit_cast(unsigned, x);
  unsigned r = (u + 0x7FFFu + ((u >> 16) & 1u)) >> 16;
  return (unsigned short)r;
}
__device__ __forceinline__ float bf16_f(unsigned short h) {
  return __builtin_bit_cast(float, ((unsigned)h) << 16);
}
__device__ __forceinline__ void split3(float x, unsigned short& h, unsigned short& m,
                                       unsigned short& l) {
  h = bf16_rne(x); float r  = x - bf16_f(h);
  m = bf16_rne(r); float r2 = r - bf16_f(m);
  l = bf16_rne(r2);
}
// pair split via v_cvt_pk_bf16_f32 (verified on gfx950: dst = {lo=cvt(src0),
// hi=cvt(src1)}; split-3 residual planes absorb any tie-rounding delta)
__device__ __forceinline__ void split3_pk(float x, float y,
                                          unsigned& ph, unsigned& pm, unsigned& pl) {
  asm("v_cvt_pk_bf16_f32 %0, %1, %2" : "=v"(ph) : "v"(x), "v"(y));
  float xh = __builtin_bit_cast(float, ph << 16);
  float yh = __builtin_bit_cast(float, ph & 0xFFFF0000u);
  float rx = x - xh, ry = y - yh;
  asm("v_cvt_pk_bf16_f32 %0, %1, %2" : "=v"(pm) : "v"(rx), "v"(ry));
  float xm = __builtin_bit_cast(float, pm << 16);
  float ym = __builtin_bit_cast(float, pm & 0xFFFF0000u);
  float r2x = rx - xm, r2y = ry - ym;
  asm("v_cvt_pk_bf16_f32 %0, %1, %2" : "=v"(pl) : "v"(r2x), "v"(r2y));
}

// ---------------------------------------------------------------------------
// K1: G0 = X @ W_emb (f64 accumulation), feat0 = relu(G0 + b_emb), out=feat0
// ---------------------------------------------------------------------------
__global__ __launch_bounds__(256) void k_embed(
    const float* __restrict__ X, const float* __restrict__ W_emb,
    const float* __restrict__ b_emb,
    float* __restrict__ G0, float* __restrict__ feat0, float* __restrict__ out)
{
  const int t = threadIdx.x;
  const int j = t & 63;
  const int node = (blockIdx.x << 2) + (t >> 6);
  const float* __restrict__ xr = X + (size_t)node * 8192;
  const float* __restrict__ wp = W_emb + j;
  double a0 = 0.0, a1 = 0.0, a2 = 0.0, a3 = 0.0;
  for (int f = 0; f < 8192; f += 4) {
    float x0 = xr[f + 0], x1 = xr[f + 1], x2 = xr[f + 2], x3 = xr[f + 3];
    a0 = fma((double)x0, (double)wp[(f + 0) << 6], a0);
    a1 = fma((double)x1, (double)wp[(f + 1) << 6], a1);
    a2 = fma((double)x2, (double)wp[(f + 2) << 6], a2);
    a3 = fma((double)x3, (double)wp[(f + 3) << 6], a3);
  }
  float g = (float)((a0 + a1) + (a2 + a3));
  const int o = node * 64 + j;
  G0[o] = g;
  float f0 = fmaxf(g + b_emb[j], 0.0f);
  feat0[o] = f0;
  out[o] = f0;
}

// ---------------------------------------------------------------------------
// K2: Y0 = feat0 @ W1b (W1 rows 64..127); Y = Y0 working copy
// ---------------------------------------------------------------------------
__global__ __launch_bounds__(128) void k_y0(
    const float* __restrict__ feat0, const float* __restrict__ W1,
    float* __restrict__ Y0, float* __restrict__ Y)
{
  const int c = threadIdx.x;
  const int i = blockIdx.x;
  const float* __restrict__ fr = feat0 + i * 64;
  float acc = 0.0f;
  #pragma unroll 8
  for (int e = 0; e < 64; ++e)
    acc = fmaf(fr[e], W1[(64 + e) * 128 + c], acc);
  Y0[i * 128 + c] = acc;
  Y[i * 128 + c] = acc;
}

// ---------------------------------------------------------------------------
// K3: serial chain, 512 threads / 8 waves. MFMA B2 (round-7 structure).
// W1T[128][130] full transposed W1. cvt_pk split-3 (verified primitive).
// Reduces via __shfl_xor, argmax via mono-key __shfl_down max + ballot
// (round-8/9's permlane16_swap / DPP row_bcast reverted — unverified
// semantics, prime suspects for the decision-cascade failures).
// ---------------------------------------------------------------------------
__global__ __launch_bounds__(512, 2) void k_serial(
    const int* __restrict__ neighbors,
    const float* __restrict__ W1, const float* __restrict__ b1,
    const float* __restrict__ W2, const float* __restrict__ b2,
    const float* __restrict__ W_lk, const float* __restrict__ b_lk,
    const float* __restrict__ W_act, const float* __restrict__ b_act,
    const float* __restrict__ b_emb,
    const float* __restrict__ G0, const float* __restrict__ feat0,
    const float* __restrict__ Y0, float* __restrict__ Y,
    float* __restrict__ feature)   // == d_out
{
  __shared__ __align__(16) float W1T[128 * 130];            // 66.6 KB full W1^T
  __shared__ __align__(16) unsigned short Ash[48 * 128];    // 12 KB h1 hi plane
  __shared__ __align__(16) unsigned short Asm[48 * 128];    // 12 KB h1 mid plane
  __shared__ __align__(16) unsigned short Asl[48 * 128];    // 12 KB h1 lo plane
  __shared__ __align__(16) float Yl[32][128];               // 16 KB
  __shared__ __align__(16) float G0l[32][64];               // 8 KB
  __shared__ __align__(16) float a1s[128];
  __shared__ __align__(16) float fis[64];
  __shared__ __align__(16) float b1s[128];
  __shared__ __align__(16) float lkps[64][4];               // [row][mt]
  __shared__ __align__(16) f32x2 p01s[64][4];               // [row][mt] {q0,q1}
  __shared__ int idxs[32];
  __shared__ int s_u, s_upd;
  __shared__ unsigned s_mu, s_mi;

  const int t = threadIdx.x;
  const int lane = t & 63;
  const int wave = t >> 6;
  const int l15 = lane & 15;
  const int lg = lane >> 4;            // 0..3
  const int mt = wave & 3;             // W2-col tile
  const int m0 = mt << 4;

  unsigned* const uAsh = (unsigned*)Ash;
  unsigned* const uAsm = (unsigned*)Asm;
  unsigned* const uAsl = (unsigned*)Asl;

  // ---- one-time staging: full transposed W1 (coalesced global reads) ----
  for (int idx = t; idx < 16384; idx += 512) {
    int e = idx >> 7, c = idx & 127;     // consecutive lanes -> consecutive c
    W1T[c * 130 + e] = W1[e * 128 + c];
  }
  if (t < 128) b1s[t] = b1[t];
  for (int idx = 33 * 64 + t; idx < 48 * 64; idx += 512) {  // zero pad rows
    uAsh[idx] = 0u; uAsm[idx] = 0u; uAsl[idx] = 0u;
  }
  const float blkv = b_lk[0];
  const float ba0 = b_act[0];
  const float ba1 = b_act[1];
  const float bembr = b_emb[lane];
  // W2^T A-frags split-3 in VGPRs: col = m0+l15, k = 32kc + 8lg + e
  bf16x8 wh[4], wm[4], wl[4];
  #pragma unroll
  for (int kc = 0; kc < 4; ++kc) {
    bf16x8 vh, vm, vl;
    #pragma unroll
    for (int e = 0; e < 8; ++e) {
      int k = (kc << 5) + (lg << 3) + e;
      float x = W2[k * 64 + m0 + l15];
      unsigned short sh, sm, sl;
      split3(x, sh, sm, sl);
      vh[e] = (short)sh; vm[e] = (short)sm; vl[e] = (short)sl;
    }
    wh[kc] = vh; wm[kc] = vm; wl[kc] = vl;
  }
  // hoisted epilogue constants
  const f32x4 c0init = *(const f32x4*)&b2[m0 + (lg << 2)];
  const f32x4 wl4 = *(const f32x4*)&W_lk[m0 + (lg << 2)];
  f32x4 wa0v, wa1v;
  #pragma unroll
  for (int r = 0; r < 4; ++r) {
    f32x2 w2a = *(const f32x2*)&W_act[(m0 + (lg << 2) + r) << 1];
    wa0v[r] = w2a[0]; wa1v[r] = w2a[1];
  }
  // hoisted B1 constants
  int kk[4]; unsigned wb[4]; const float2* ylp[4];
  #pragma unroll
  for (int n = 0; n < 4; ++n) {
    kk[n] = wave + (n << 3);
    wb[n] = (unsigned)((kk[n] << 6) + (lane ^ ((kk[n] & 7) << 2)));
    ylp[n] = (const float2*)&Yl[kk[n]][lane << 1];
  }
  const unsigned wb32 = 2048u + (unsigned)lane;   // row 32, swz=0
  // hoisted B2 read offsets (ushort units)
  const int ntA = (wave < 4) ? 0 : 1;
  const int rowA = (ntA << 4) + l15;
  const int rowB = 32 + l15;                       // only waves 0-3
  int aoA[4], aoB[4];
  #pragma unroll
  for (int kc = 0; kc < 4; ++kc) {
    aoA[kc] = (rowA << 7) + ((((kc << 2) + lg) ^ (rowA & 7)) << 3);
    aoB[kc] = (rowB << 7) + ((((kc << 2) + lg) ^ (rowB & 7)) << 3);
  }
  const float2* const a1p = (const float2*)&a1s[lane << 1];
  // wave-0 register state
  unsigned vm = 0xFFFFFFFFu; float cntf = 0.f; int done = 0;
  int ridx = 0; float gisr = 0.f, sumgr = 0.f;
  __syncthreads();

  for (int i = 0; i < 1024; ++i) {
    // ---- phase0: per-node prefetch ----
    #pragma unroll
    for (int p = 0; p < 2; ++p) {
      int fi = (p << 9) + t;               // 0..1023
      int k = fi >> 5;
      int c4 = (fi & 31) << 2;
      int v = neighbors[(i << 5) + k];
      *(float4*)&Yl[k][c4] = *(const float4*)&Y[v * 128 + c4];
    }
    {
      int k = t >> 4;                      // 0..31
      int c4 = (t & 15) << 2;
      int v = neighbors[(i << 5) + k];
      *(float4*)&G0l[k][c4] = *(const float4*)&G0[v * 64 + c4];
    }
    if (t < 64) fis[t] = feature[(i << 6) + t];
    if (t < 32) idxs[t] = neighbors[(i << 5) + t];
    __syncthreads();
    // ---- a1 = fi @ W1a + b1 (W1T b64 reads; chain bit-identical) ----
    if (t < 128) {
      float aa0 = b1s[t], aa1 = 0.0f;
      const float* w1r = &W1T[t * 130];
      #pragma unroll 8
      for (int e = 0; e < 64; e += 2) {
        f32x2 wv = *(const f32x2*)&w1r[e];
        aa0 = fmaf(fis[e],     wv[0], aa0);
        aa1 = fmaf(fis[e + 1], wv[1], aa1);
      }
      a1s[t] = aa0 + aa1;
    }
    int vn[4];
    #pragma unroll
    for (int n = 0; n < 4; ++n) vn[n] = idxs[kk[n]];
    if (wave == 0) {
      ridx = idxs[lane & 31];
      gisr = G0[(i << 6) + lane];
      sumgr = 0.f; vm = 0xFFFFFFFFu; cntf = 0.f; done = 0;
    }
    __syncthreads();

    for (int st = 0; st < 3; ++st) {
      // ---- B1: 4 rows/wave (+row 32 by wave 4); cvt_pk split-3 ----
      {
        float2 av = *a1p;
        #pragma unroll
        for (int n = 0; n < 4; ++n) {
          float hx = av.x, hy = av.y;
          if (vn[n] > 0) {                         // wave-uniform branch
            float2 yv = *ylp[n];
            hx += yv.x; hy += yv.y;
          }
          hx = fmaxf(hx, 0.f); hy = fmaxf(hy, 0.f);
          unsigned ph, pm, pl;
          split3_pk(hx, hy, ph, pm, pl);
          uAsh[wb[n]] = ph; uAsm[wb[n]] = pm; uAsl[wb[n]] = pl;
        }
        if (wave == 4) {
          float hx = fmaxf(av.x, 0.f), hy = fmaxf(av.y, 0.f);
          unsigned ph, pm, pl;
          split3_pk(hx, hy, ph, pm, pl);
          uAsh[wb32] = ph; uAsm[wb32] = pm; uAsl[wb32] = pl;
        }
      }
      __syncthreads();
      // ---- B2: MFMA tiles (waves 0-3: rows 0-15 & 32-47; waves 4-7: 16-31) --
      {
        f32x4 cA = c0init, cB = c0init;
        const bool twoT = (wave < 4);
        #pragma unroll
        for (int kc = 0; kc < 4; ++kc) {
          bf16x8 ahA = *(const bf16x8*)&Ash[aoA[kc]];
          bf16x8 amA = *(const bf16x8*)&Asm[aoA[kc]];
          bf16x8 alA = *(const bf16x8*)&Asl[aoA[kc]];
          cA = __builtin_amdgcn_mfma_f32_16x16x32_bf16(wh[kc], ahA, cA, 0, 0, 0);
          cA = __builtin_amdgcn_mfma_f32_16x16x32_bf16(wh[kc], amA, cA, 0, 0, 0);
          cA = __builtin_amdgcn_mfma_f32_16x16x32_bf16(wm[kc], ahA, cA, 0, 0, 0);
          cA = __builtin_amdgcn_mfma_f32_16x16x32_bf16(wh[kc], alA, cA, 0, 0, 0);
          cA = __builtin_amdgcn_mfma_f32_16x16x32_bf16(wl[kc], ahA, cA, 0, 0, 0);
          cA = __builtin_amdgcn_mfma_f32_16x16x32_bf16(wm[kc], amA, cA, 0, 0, 0);
          if (twoT) {
            bf16x8 ahB = *(const bf16x8*)&Ash[aoB[kc]];
            bf16x8 amB = *(const bf16x8*)&Asm[aoB[kc]];
            bf16x8 alB = *(const bf16x8*)&Asl[aoB[kc]];
            cB = __builtin_amdgcn_mfma_f32_16x16x32_bf16(wh[kc], ahB, cB, 0, 0, 0);
            cB = __builtin_amdgcn_mfma_f32_16x16x32_bf16(wh[kc], amB, cB, 0, 0, 0);
            cB = __builtin_amdgcn_mfma_f32_16x16x32_bf16(wm[kc], ahB, cB, 0, 0, 0);
            cB = __builtin_amdgcn_mfma_f32_16x16x32_bf16(wh[kc], alB, cB, 0, 0, 0);
            cB = __builtin_amdgcn_mfma_f32_16x16x32_bf16(wl[kc], ahB, cB, 0, 0, 0);
            cB = __builtin_amdgcn_mfma_f32_16x16x32_bf16(wm[kc], amB, cB, 0, 0, 0);
          }
        }
        // epilogue A
        {
          float pl = 0.f, q0 = 0.f, q1 = 0.f;
          #pragma unroll
          for (int r = 0; r < 4; ++r) {
            float v = fmaxf(cA[r], 0.f);
            pl = fmaf(v, wl4[r], pl);
            q0 = fmaf(v, wa0v[r], q0);
            q1 = fmaf(v, wa1v[r], q1);
          }
          pl += __shfl_xor(pl, 16); pl += __shfl_xor(pl, 32);
          q0 += __shfl_xor(q0, 16); q0 += __shfl_xor(q0, 32);
          q1 += __shfl_xor(q1, 16); q1 += __shfl_xor(q1, 32);
          if (lg == 0) {
            lkps[rowA][mt] = pl;
            p01s[rowA][mt] = (f32x2){q0, q1};
          }
        }
        if (twoT) {
          float pl = 0.f, q0 = 0.f, q1 = 0.f;
          #pragma unroll
          for (int r = 0; r < 4; ++r) {
            float v = fmaxf(cB[r], 0.f);
            pl = fmaf(v, wl4[r], pl);
            q0 = fmaf(v, wa0v[r], q0);
            q1 = fmaf(v, wa1v[r], q1);
          }
          pl += __shfl_xor(pl, 16); pl += __shfl_xor(pl, 32);
          q0 += __shfl_xor(q0, 16); q0 += __shfl_xor(q0, 32);
          q1 += __shfl_xor(q1, 16); q1 += __shfl_xor(q1, 32);
          if (lg == 0) {
            lkps[rowB][mt] = pl;
            p01s[rowB][mt] = (f32x2){q0, q1};
          }
        }
      }
      __syncthreads();
      // ---- P4+D (wave 0): mono-key shfl_down max + ballot argmax ----
      if (wave == 0) {
        f32x4 lk4 = *(const f32x4*)&lkps[lane][0];
        float lkv = ((lk4[0] + lk4[1]) + (lk4[2] + lk4[3])) + blkv;
        unsigned b = __builtin_bit_cast(unsigned, lkv);
        int sb = (int)b >> 31;
        unsigned mono = b ^ (0x80000000u | (unsigned)sb);
        bool valid = (lane == 32) || ((lane < 32) && ((vm >> lane) & 1u));
        unsigned key = valid ? mono : 0u;
        unsigned red = key;
        #pragma unroll
        for (int off = 32; off; off >>= 1) {
          unsigned o = (unsigned)__shfl_down((int)red, off);
          red = red > o ? red : o;
        }
        unsigned vmax = (unsigned)__shfl((int)red, 0);
        unsigned long long am = __ballot(valid && (key == vmax));
        const int ut = (int)(__ffsll(am) - 1);
        const int utc = ut < 31 ? ut : 31;
        f32x2 a01 = p01s[utc][0], b01 = p01s[utc][1];
        f32x2 c01 = p01s[utc][2], d01 = p01s[utc][3];
        float d0 = ((a01[0] + b01[0]) + (c01[0] + d01[0])) + ba0;
        float d1 = ((a01[1] + b01[1]) + (c01[1] + d01[1])) + ba1;
        const int at1 = (d1 > d0) ? 1 : 0;
        const int newdone = done | (ut == 32);
        const int upd = newdone ? 0 : 1;
        done = newdone;
        const float take = at1 ? 1.0f : 0.0f;
        const float denom = cntf + take + 1.0f;
        const int u = __builtin_amdgcn_readlane(ridx, utc);
        unsigned long long bu = __ballot(lane < 32 && ridx == u);
        unsigned long long bi = __ballot(lane < 32 && ridx == i);
        if (lane == 0) {
          s_u = u; s_upd = upd;
          s_mu = (unsigned)bu; s_mi = (unsigned)bi;
        }
        if (upd) {
          vm &= ~(1u << utc);
          cntf += take;
          const float gu = G0l[utc][lane];
          const float ns = sumgr + take * gu;
          const float hv = (ns + gisr) / denom;
          const float nfi = fmaxf(hv + bembr, 0.0f);
          sumgr = ns;
          const float f0u = fmaxf(gu + bembr, 0.0f);   // == feat0[u] bit-exact
          feature[(i << 6) + lane] = nfi;              // feature[u] wins if u==i
          feature[(u << 6) + lane] = f0u;
          fis[lane] = (u == i) ? f0u : nfi;
        }
      }
      __syncthreads();
      if (!s_upd) break;
      // ---- E: waves 0-1 -> Y rows + Yl patches; waves 2-3 -> a1 ----
      if (wave < 4) {
        const int u = s_u;
        const int c = t & 127;
        const float* w1r = &W1T[c * 130];
        if (wave < 2) {
          const float yu = Y0[u * 128 + c];            // early, overlaps FMAs
          f32x2 acc = {0.f, 0.f};
          #pragma unroll 8
          for (int e = 0; e < 64; e += 2) {
            f32x2 fv = *(const f32x2*)&fis[e];
            f32x2 wv = *(const f32x2*)&w1r[64 + e];
            acc = __builtin_elementwise_fma(fv, wv, acc);
          }
          const float yi = acc[0] + acc[1];
          Y[i * 128 + c] = yi;                         // Y[u] wins if u==i
          Y[u * 128 + c] = yu;
          const unsigned mu = s_mu;
          for (unsigned m = mu; m; m &= m - 1) {
            int k = __ffs(m) - 1;
            Yl[k][c] = yu;
          }
          for (unsigned m = s_mi & ~mu; m; m &= m - 1) {
            int k = __ffs(m) - 1;
            Yl[k][c] = yi;
          }
        } else {
          f32x2 aa = {b1s[c], 0.f};
          #pragma unroll 8
          for (int e = 0; e < 64; e += 2) {
            f32x2 fv = *(const f32x2*)&fis[e];
            f32x2 wv = *(const f32x2*)&w1r[e];
            aa = __builtin_elementwise_fma(fv, wv, aa);
          }
          a1s[c] = aa[0] + aa[1];
        }
      }
      __syncthreads();
    }
  }
}

// ---------------------------------------------------------------------------
extern "C" void kernel_launch(void* const* d_in, const int* in_sizes, int n_in,
                              void* d_out, int out_size, void* d_ws, size_t ws_size,
                              hipStream_t stream) {
  const float* X     = (const float*)d_in[0];
  const int*   nbr   = (const int*)  d_in[1];
  const float* W_emb = (const float*)d_in[2];
  const float* b_emb = (const float*)d_in[3];
  const float* W1    = (const float*)d_in[4];
  const float* b1    = (const float*)d_in[5];
  const float* W2    = (const float*)d_in[6];
  const float* b2    = (const float*)d_in[7];
  const float* W_lk  = (const float*)d_in[8];
  const float* b_lk  = (const float*)d_in[9];
  const float* W_act = (const float*)d_in[10];
  const float* b_act = (const float*)d_in[11];
  float* out = (float*)d_out;
  float* ws  = (float*)d_ws;
  float* G0    = ws;             // [1024*64]
  float* feat0 = ws + 65536;     // [1024*64]
  float* Y0    = ws + 131072;    // [1024*128]
  float* Y     = ws + 262144;    // [1024*128]

  hipLaunchKernelGGL(k_embed, dim3(256), dim3(256), 0, stream,
                     X, W_emb, b_emb, G0, feat0, out);
  hipLaunchKernelGGL(k_y0, dim3(1024), dim3(128), 0, stream,
                     feat0, W1, Y0, Y);
  hipLaunchKernelGGL(k_serial, dim3(1), dim3(512), 0, stream,
                     nbr, W1, b1, W2, b2, W_lk, b_lk, W_act, b_act, b_emb,
                     G0, feat0, Y0, Y, out);
}

// Round 11
// 9202.463 us; speedup vs baseline: 15.6534x; 1.0466x over previous
//
#include <hip/hip_runtime.h>

// Problem constants: N=1024, K=32, F=8192, E=64, H1=128, H2=64, T=3

typedef float f32x4 __attribute__((ext_vector_type(4)));
typedef float f32x2 __attribute__((ext_vector_type(2)));
typedef short bf16x8 __attribute__((ext_vector_type(8)));

__device__ __forceinline__ unsigned short bf16_rne(float x) {
  unsigned u = __builtin_bit_cast(unsigned, x);
  unsigned r = (u + 0x7FFFu + ((u >> 16) & 1u)) >> 16;
  return (unsigned short)r;
}
__device__ __forceinline__ float bf16_f(unsigned short h) {
  return __builtin_bit_cast(float, ((unsigned)h) << 16);
}
__device__ __forceinline__ void split3(float x, unsigned short& h, unsigned short& m,
                                       unsigned short& l) {
  h = bf16_rne(x); float r  = x - bf16_f(h);
  m = bf16_rne(r); float r2 = r - bf16_f(m);
  l = bf16_rne(r2);
}
// pair split via v_cvt_pk_bf16_f32 (verified on gfx950: dst = {lo=cvt(src0),
// hi=cvt(src1)}; split-3 residual planes absorb any tie-rounding delta)
__device__ __forceinline__ void split3_pk(float x, float y,
                                          unsigned& ph, unsigned& pm, unsigned& pl) {
  asm("v_cvt_pk_bf16_f32 %0, %1, %2" : "=v"(ph) : "v"(x), "v"(y));
  float xh = __builtin_bit_cast(float, ph << 16);
  float yh = __builtin_bit_cast(float, ph & 0xFFFF0000u);
  float rx = x - xh, ry = y - yh;
  asm("v_cvt_pk_bf16_f32 %0, %1, %2" : "=v"(pm) : "v"(rx), "v"(ry));
  float xm = __builtin_bit_cast(float, pm << 16);
  float ym = __builtin_bit_cast(float, pm & 0xFFFF0000u);
  float r2x = rx - xm, r2y = ry - ym;
  asm("v_cvt_pk_bf16_f32 %0, %1, %2" : "=v"(pl) : "v"(r2x), "v"(r2y));
}

// ---------------------------------------------------------------------------
// K1: G0 = X @ W_emb (f64 accumulation), feat0 = relu(G0 + b_emb), out=feat0
// ---------------------------------------------------------------------------
__global__ __launch_bounds__(256) void k_embed(
    const float* __restrict__ X, const float* __restrict__ W_emb,
    const float* __restrict__ b_emb,
    float* __restrict__ G0, float* __restrict__ feat0, float* __restrict__ out)
{
  const int t = threadIdx.x;
  const int j = t & 63;
  const int node = (blockIdx.x << 2) + (t >> 6);
  const float* __restrict__ xr = X + (size_t)node * 8192;
  const float* __restrict__ wp = W_emb + j;
  double a0 = 0.0, a1 = 0.0, a2 = 0.0, a3 = 0.0;
  for (int f = 0; f < 8192; f += 4) {
    float x0 = xr[f + 0], x1 = xr[f + 1], x2 = xr[f + 2], x3 = xr[f + 3];
    a0 = fma((double)x0, (double)wp[(f + 0) << 6], a0);
    a1 = fma((double)x1, (double)wp[(f + 1) << 6], a1);
    a2 = fma((double)x2, (double)wp[(f + 2) << 6], a2);
    a3 = fma((double)x3, (double)wp[(f + 3) << 6], a3);
  }
  float g = (float)((a0 + a1) + (a2 + a3));
  const int o = node * 64 + j;
  G0[o] = g;
  float f0 = fmaxf(g + b_emb[j], 0.0f);
  feat0[o] = f0;
  out[o] = f0;
}

// ---------------------------------------------------------------------------
// K2: Y0 = feat0 @ W1b (W1 rows 64..127); Y = Y0 working copy
// ---------------------------------------------------------------------------
__global__ __launch_bounds__(128) void k_y0(
    const float* __restrict__ feat0, const float* __restrict__ W1,
    float* __restrict__ Y0, float* __restrict__ Y)
{
  const int c = threadIdx.x;
  const int i = blockIdx.x;
  const float* __restrict__ fr = feat0 + i * 64;
  float acc = 0.0f;
  #pragma unroll 8
  for (int e = 0; e < 64; ++e)
    acc = fmaf(fr[e], W1[(64 + e) * 128 + c], acc);
  Y0[i * 128 + c] = acc;
  Y[i * 128 + c] = acc;
}

// ---------------------------------------------------------------------------
// K3: serial chain, 512 threads / 8 waves. MFMA B2.
// Round-11: B2 epilogue stores RAW lg-partials (no shfl); P4 assembles lk with
// bit-identical nesting and does argmax via LDS keybuf round-trip (no shfl
// chain). Only proven primitives (shfl for nothing; ballot/ffsll/readlane).
// ---------------------------------------------------------------------------
__global__ __launch_bounds__(512, 2) void k_serial(
    const int* __restrict__ neighbors,
    const float* __restrict__ W1, const float* __restrict__ b1,
    const float* __restrict__ W2, const float* __restrict__ b2,
    const float* __restrict__ W_lk, const float* __restrict__ b_lk,
    const float* __restrict__ W_act, const float* __restrict__ b_act,
    const float* __restrict__ b_emb,
    const float* __restrict__ G0, const float* __restrict__ feat0,
    const float* __restrict__ Y0, float* __restrict__ Y,
    float* __restrict__ feature)   // == d_out
{
  __shared__ __align__(16) float W1T[128 * 130];            // 66.6 KB full W1^T
  __shared__ __align__(16) unsigned short Ash[48 * 128];    // 12 KB h1 hi plane
  __shared__ __align__(16) unsigned short Asm[48 * 128];    // 12 KB h1 mid plane
  __shared__ __align__(16) unsigned short Asl[48 * 128];    // 12 KB h1 lo plane
  __shared__ __align__(16) float Yl[32][128];               // 16 KB
  __shared__ __align__(16) float G0l[32][64];               // 8 KB
  __shared__ __align__(16) float a1s[128];
  __shared__ __align__(16) float fis[64];
  __shared__ __align__(16) float b1s[128];
  __shared__ __align__(16) float lkrawT[16][64];            // 4 KB  [c=(mt,lg)][row]
  __shared__ __align__(16) f32x2 p01rawT[16][32];           // 4 KB  [c][row<32]
  __shared__ __align__(16) unsigned keybuf[64];
  __shared__ int idxs[32];
  __shared__ int s_u, s_upd;
  __shared__ unsigned s_mu, s_mi;

  const int t = threadIdx.x;
  const int lane = t & 63;
  const int wave = t >> 6;
  const int l15 = lane & 15;
  const int lg = lane >> 4;            // 0..3
  const int mt = wave & 3;             // W2-col tile
  const int m0 = mt << 4;
  const int c16 = (mt << 2) + lg;      // raw-partial column id

  unsigned* const uAsh = (unsigned*)Ash;
  unsigned* const uAsm = (unsigned*)Asm;
  unsigned* const uAsl = (unsigned*)Asl;

  // ---- one-time staging: full transposed W1 (coalesced global reads) ----
  for (int idx = t; idx < 16384; idx += 512) {
    int e = idx >> 7, c = idx & 127;     // consecutive lanes -> consecutive c
    W1T[c * 130 + e] = W1[e * 128 + c];
  }
  if (t < 128) b1s[t] = b1[t];
  for (int idx = 33 * 64 + t; idx < 48 * 64; idx += 512) {  // zero pad rows
    uAsh[idx] = 0u; uAsm[idx] = 0u; uAsl[idx] = 0u;
  }
  const float blkv = b_lk[0];
  const float ba0 = b_act[0];
  const float ba1 = b_act[1];
  const float bembr = b_emb[lane];
  // W2^T A-frags split-3 in VGPRs: col = m0+l15, k = 32kc + 8lg + e
  bf16x8 wh[4], wm[4], wl[4];
  #pragma unroll
  for (int kc = 0; kc < 4; ++kc) {
    bf16x8 vh, vm, vl;
    #pragma unroll
    for (int e = 0; e < 8; ++e) {
      int k = (kc << 5) + (lg << 3) + e;
      float x = W2[k * 64 + m0 + l15];
      unsigned short sh, sm, sl;
      split3(x, sh, sm, sl);
      vh[e] = (short)sh; vm[e] = (short)sm; vl[e] = (short)sl;
    }
    wh[kc] = vh; wm[kc] = vm; wl[kc] = vl;
  }
  // hoisted epilogue constants
  const f32x4 c0init = *(const f32x4*)&b2[m0 + (lg << 2)];
  const f32x4 wl4 = *(const f32x4*)&W_lk[m0 + (lg << 2)];
  f32x4 wa0v, wa1v;
  #pragma unroll
  for (int r = 0; r < 4; ++r) {
    f32x2 w2a = *(const f32x2*)&W_act[(m0 + (lg << 2) + r) << 1];
    wa0v[r] = w2a[0]; wa1v[r] = w2a[1];
  }
  // hoisted B1 constants
  int kk[4]; unsigned wb[4]; const float2* ylp[4];
  #pragma unroll
  for (int n = 0; n < 4; ++n) {
    kk[n] = wave + (n << 3);
    wb[n] = (unsigned)((kk[n] << 6) + (lane ^ ((kk[n] & 7) << 2)));
    ylp[n] = (const float2*)&Yl[kk[n]][lane << 1];
  }
  const unsigned wb32 = 2048u + (unsigned)lane;   // row 32, swz=0
  // hoisted B2 read offsets (ushort units)
  const int ntA = (wave < 4) ? 0 : 1;
  const int rowA = (ntA << 4) + l15;
  const int rowB = 32 + l15;                       // only waves 0-3
  int aoA[4], aoB[4];
  #pragma unroll
  for (int kc = 0; kc < 4; ++kc) {
    aoA[kc] = (rowA << 7) + ((((kc << 2) + lg) ^ (rowA & 7)) << 3);
    aoB[kc] = (rowB << 7) + ((((kc << 2) + lg) ^ (rowB & 7)) << 3);
  }
  const float2* const a1p = (const float2*)&a1s[lane << 1];
  // wave-0 register state
  unsigned vm = 0xFFFFFFFFu; float cntf = 0.f; int done = 0;
  int ridx = 0; float gisr = 0.f, sumgr = 0.f;
  __syncthreads();

  for (int i = 0; i < 1024; ++i) {
    // ---- phase0: per-node prefetch ----
    #pragma unroll
    for (int p = 0; p < 2; ++p) {
      int fi = (p << 9) + t;               // 0..1023
      int k = fi >> 5;
      int c4 = (fi & 31) << 2;
      int v = neighbors[(i << 5) + k];
      *(float4*)&Yl[k][c4] = *(const float4*)&Y[v * 128 + c4];
    }
    {
      int k = t >> 4;                      // 0..31
      int c4 = (t & 15) << 2;
      int v = neighbors[(i << 5) + k];
      *(float4*)&G0l[k][c4] = *(const float4*)&G0[v * 64 + c4];
    }
    if (t < 64) fis[t] = feature[(i << 6) + t];
    if (t < 32) idxs[t] = neighbors[(i << 5) + t];
    __syncthreads();
    // ---- a1 = fi @ W1a + b1 (W1T b64 reads; chain bit-identical) ----
    if (t < 128) {
      float aa0 = b1s[t], aa1 = 0.0f;
      const float* w1r = &W1T[t * 130];
      #pragma unroll 8
      for (int e = 0; e < 64; e += 2) {
        f32x2 wv = *(const f32x2*)&w1r[e];
        aa0 = fmaf(fis[e],     wv[0], aa0);
        aa1 = fmaf(fis[e + 1], wv[1], aa1);
      }
      a1s[t] = aa0 + aa1;
    }
    int vn[4];
    #pragma unroll
    for (int n = 0; n < 4; ++n) vn[n] = idxs[kk[n]];
    if (wave == 0) {
      ridx = idxs[lane & 31];
      gisr = G0[(i << 6) + lane];
      sumgr = 0.f; vm = 0xFFFFFFFFu; cntf = 0.f; done = 0;
    }
    __syncthreads();

    for (int st = 0; st < 3; ++st) {
      // ---- B1: 4 rows/wave (+row 32 by wave 4); cvt_pk split-3 ----
      {
        float2 av = *a1p;
        #pragma unroll
        for (int n = 0; n < 4; ++n) {
          float hx = av.x, hy = av.y;
          if (vn[n] > 0) {                         // wave-uniform branch
            float2 yv = *ylp[n];
            hx += yv.x; hy += yv.y;
          }
          hx = fmaxf(hx, 0.f); hy = fmaxf(hy, 0.f);
          unsigned ph, pm, pl;
          split3_pk(hx, hy, ph, pm, pl);
          uAsh[wb[n]] = ph; uAsm[wb[n]] = pm; uAsl[wb[n]] = pl;
        }
        if (wave == 4) {
          float hx = fmaxf(av.x, 0.f), hy = fmaxf(av.y, 0.f);
          unsigned ph, pm, pl;
          split3_pk(hx, hy, ph, pm, pl);
          uAsh[wb32] = ph; uAsm[wb32] = pm; uAsl[wb32] = pl;
        }
      }
      __syncthreads();
      // ---- B2: MFMA tiles (waves 0-3: rows 0-15 & 32-47; waves 4-7: 16-31) --
      {
        f32x4 cA = c0init, cB = c0init;
        const bool twoT = (wave < 4);
        #pragma unroll
        for (int kc = 0; kc < 4; ++kc) {
          bf16x8 ahA = *(const bf16x8*)&Ash[aoA[kc]];
          bf16x8 amA = *(const bf16x8*)&Asm[aoA[kc]];
          bf16x8 alA = *(const bf16x8*)&Asl[aoA[kc]];
          cA = __builtin_amdgcn_mfma_f32_16x16x32_bf16(wh[kc], ahA, cA, 0, 0, 0);
          cA = __builtin_amdgcn_mfma_f32_16x16x32_bf16(wh[kc], amA, cA, 0, 0, 0);
          cA = __builtin_amdgcn_mfma_f32_16x16x32_bf16(wm[kc], ahA, cA, 0, 0, 0);
          cA = __builtin_amdgcn_mfma_f32_16x16x32_bf16(wh[kc], alA, cA, 0, 0, 0);
          cA = __builtin_amdgcn_mfma_f32_16x16x32_bf16(wl[kc], ahA, cA, 0, 0, 0);
          cA = __builtin_amdgcn_mfma_f32_16x16x32_bf16(wm[kc], amA, cA, 0, 0, 0);
          if (twoT) {
            bf16x8 ahB = *(const bf16x8*)&Ash[aoB[kc]];
            bf16x8 amB = *(const bf16x8*)&Asm[aoB[kc]];
            bf16x8 alB = *(const bf16x8*)&Asl[aoB[kc]];
            cB = __builtin_amdgcn_mfma_f32_16x16x32_bf16(wh[kc], ahB, cB, 0, 0, 0);
            cB = __builtin_amdgcn_mfma_f32_16x16x32_bf16(wh[kc], amB, cB, 0, 0, 0);
            cB = __builtin_amdgcn_mfma_f32_16x16x32_bf16(wm[kc], ahB, cB, 0, 0, 0);
            cB = __builtin_amdgcn_mfma_f32_16x16x32_bf16(wh[kc], alB, cB, 0, 0, 0);
            cB = __builtin_amdgcn_mfma_f32_16x16x32_bf16(wl[kc], ahB, cB, 0, 0, 0);
            cB = __builtin_amdgcn_mfma_f32_16x16x32_bf16(wm[kc], amB, cB, 0, 0, 0);
          }
        }
        // epilogue A: raw per-lg partials (no shfl)
        {
          float pl = 0.f, q0 = 0.f, q1 = 0.f;
          #pragma unroll
          for (int r = 0; r < 4; ++r) {
            float v = fmaxf(cA[r], 0.f);
            pl = fmaf(v, wl4[r], pl);
            q0 = fmaf(v, wa0v[r], q0);
            q1 = fmaf(v, wa1v[r], q1);
          }
          lkrawT[c16][rowA] = pl;
          p01rawT[c16][rowA] = (f32x2){q0, q1};
        }
        if (twoT) {   // row 32 never feeds the action head: lk partial only
          float pl = 0.f;
          #pragma unroll
          for (int r = 0; r < 4; ++r) {
            float v = fmaxf(cB[r], 0.f);
            pl = fmaf(v, wl4[r], pl);
          }
          lkrawT[c16][rowB] = pl;
        }
      }
      __syncthreads();
      // ---- P4+D (wave 0): assemble lk (bit-identical nesting), LDS-key
      //      argmax (no shfl chain), action head, state update ----
      if (wave == 0) {
        float v_[16];
        #pragma unroll
        for (int c = 0; c < 16; ++c) v_[c] = lkrawT[c][lane];
        float s0 = (v_[0] + v_[1]) + (v_[2] + v_[3]);
        float s1 = (v_[4] + v_[5]) + (v_[6] + v_[7]);
        float s2 = (v_[8] + v_[9]) + (v_[10] + v_[11]);
        float s3 = (v_[12] + v_[13]) + (v_[14] + v_[15]);
        float lkv = ((s0 + s1) + (s2 + s3)) + blkv;
        unsigned b = __builtin_bit_cast(unsigned, lkv);
        int sb = (int)b >> 31;
        unsigned mono = b ^ (0x80000000u | (unsigned)sb);
        bool valid = (lane == 32) || ((lane < 32) && ((vm >> lane) & 1u));
        unsigned key = valid ? mono : 0u;
        keybuf[lane] = key;
        asm volatile("s_waitcnt lgkmcnt(0)" ::: "memory");
        __builtin_amdgcn_sched_barrier(0);
        const uint4* kb = (const uint4*)keybuf;
        unsigned mx = 0u;
        #pragma unroll
        for (int c = 0; c < 16; ++c) {
          uint4 kv = kb[c];
          unsigned m01 = kv.x > kv.y ? kv.x : kv.y;
          unsigned m23 = kv.z > kv.w ? kv.z : kv.w;
          unsigned mm = m01 > m23 ? m01 : m23;
          mx = mx > mm ? mx : mm;
        }
        unsigned long long am = __ballot(valid && (key == mx));
        const int ut = (int)(__ffsll(am) - 1);
        const int utc = ut < 31 ? ut : 31;
        // action head: broadcast reads of raw partials at utc, same nesting
        f32x2 q[16];
        #pragma unroll
        for (int c = 0; c < 16; ++c) q[c] = p01rawT[c][utc];
        f32x2 S0 = (q[0] + q[1]) + (q[2] + q[3]);
        f32x2 S1 = (q[4] + q[5]) + (q[6] + q[7]);
        f32x2 S2 = (q[8] + q[9]) + (q[10] + q[11]);
        f32x2 S3 = (q[12] + q[13]) + (q[14] + q[15]);
        f32x2 D01 = (S0 + S1) + (S2 + S3);
        float d0 = D01[0] + ba0;
        float d1 = D01[1] + ba1;
        const int at1 = (d1 > d0) ? 1 : 0;
        const int newdone = done | (ut == 32);
        const int upd = newdone ? 0 : 1;
        done = newdone;
        const float take = at1 ? 1.0f : 0.0f;
        const float denom = cntf + take + 1.0f;
        const int u = __builtin_amdgcn_readlane(ridx, utc);
        unsigned long long bu = __ballot(lane < 32 && ridx == u);
        unsigned long long bi = __ballot(lane < 32 && ridx == i);
        if (lane == 0) {
          s_u = u; s_upd = upd;
          s_mu = (unsigned)bu; s_mi = (unsigned)bi;
        }
        if (upd) {
          vm &= ~(1u << utc);
          cntf += take;
          const float gu = G0l[utc][lane];
          const float ns = sumgr + take * gu;
          const float hv = (ns + gisr) / denom;
          const float nfi = fmaxf(hv + bembr, 0.0f);
          sumgr = ns;
          const float f0u = fmaxf(gu + bembr, 0.0f);   // == feat0[u] bit-exact
          feature[(i << 6) + lane] = nfi;              // feature[u] wins if u==i
          feature[(u << 6) + lane] = f0u;
          fis[lane] = (u == i) ? f0u : nfi;
        }
      }
      __syncthreads();
      if (!s_upd) break;
      // ---- E: waves 0-1 -> Y rows + Yl patches; waves 2-3 -> a1 ----
      if (wave < 4) {
        const int u = s_u;
        const int c = t & 127;
        const float* w1r = &W1T[c * 130];
        if (wave < 2) {
          const float yu = Y0[u * 128 + c];            // early, overlaps FMAs
          f32x2 acc = {0.f, 0.f};
          #pragma unroll 8
          for (int e = 0; e < 64; e += 2) {
            f32x2 fv = *(const f32x2*)&fis[e];
            f32x2 wv = *(const f32x2*)&w1r[64 + e];
            acc = __builtin_elementwise_fma(fv, wv, acc);
          }
          const float yi = acc[0] + acc[1];
          Y[i * 128 + c] = yi;                         // Y[u] wins if u==i
          Y[u * 128 + c] = yu;
          const unsigned mu = s_mu;
          for (unsigned m = mu; m; m &= m - 1) {
            int k = __ffs(m) - 1;
            Yl[k][c] = yu;
          }
          for (unsigned m = s_mi & ~mu; m; m &= m - 1) {
            int k = __ffs(m) - 1;
            Yl[k][c] = yi;
          }
        } else {
          f32x2 aa = {b1s[c], 0.f};
          #pragma unroll 8
          for (int e = 0; e < 64; e += 2) {
            f32x2 fv = *(const f32x2*)&fis[e];
            f32x2 wv = *(const f32x2*)&w1r[e];
            aa = __builtin_elementwise_fma(fv, wv, aa);
          }
          a1s[c] = aa[0] + aa[1];
        }
      }
      __syncthreads();
    }
  }
}

// ---------------------------------------------------------------------------
extern "C" void kernel_launch(void* const* d_in, const int* in_sizes, int n_in,
                              void* d_out, int out_size, void* d_ws, size_t ws_size,
                              hipStream_t stream) {
  const float* X     = (const float*)d_in[0];
  const int*   nbr   = (const int*)  d_in[1];
  const float* W_emb = (const float*)d_in[2];
  const float* b_emb = (const float*)d_in[3];
  const float* W1    = (const float*)d_in[4];
  const float* b1    = (const float*)d_in[5];
  const float* W2    = (const float*)d_in[6];
  const float* b2    = (const float*)d_in[7];
  const float* W_lk  = (const float*)d_in[8];
  const float* b_lk  = (const float*)d_in[9];
  const float* W_act = (const float*)d_in[10];
  const float* b_act = (const float*)d_in[11];
  float* out = (float*)d_out;
  float* ws  = (float*)d_ws;
  float* G0    = ws;             // [1024*64]
  float* feat0 = ws + 65536;     // [1024*64]
  float* Y0    = ws + 131072;    // [1024*128]
  float* Y     = ws + 262144;    // [1024*128]

  hipLaunchKernelGGL(k_embed, dim3(256), dim3(256), 0, stream,
                     X, W_emb, b_emb, G0, feat0, out);
  hipLaunchKernelGGL(k_y0, dim3(1024), dim3(128), 0, stream,
                     feat0, W1, Y0, Y);
  hipLaunchKernelGGL(k_serial, dim3(1), dim3(512), 0, stream,
                     nbr, W1, b1, W2, b2, W_lk, b_lk, W_act, b_act, b_emb,
                     G0, feat0, Y0, Y, out);
}

// Round 12
// 9194.341 us; speedup vs baseline: 15.6673x; 1.0009x over previous
//
#include <hip/hip_runtime.h>

// Problem constants: N=1024, K=32, F=8192, E=64, H1=128, H2=64, T=3

typedef float f32x4 __attribute__((ext_vector_type(4)));
typedef float f32x2 __attribute__((ext_vector_type(2)));
typedef short bf16x8 __attribute__((ext_vector_type(8)));

__device__ __forceinline__ unsigned short bf16_rne(float x) {
  unsigned u = __builtin_bit_cast(unsigned, x);
  unsigned r = (u + 0x7FFFu + ((u >> 16) & 1u)) >> 16;
  return (unsigned short)r;
}
__device__ __forceinline__ float bf16_f(unsigned short h) {
  return __builtin_bit_cast(float, ((unsigned)h) << 16);
}
__device__ __forceinline__ void split3(float x, unsigned short& h, unsigned short& m,
                                       unsigned short& l) {
  h = bf16_rne(x); float r  = x - bf16_f(h);
  m = bf16_rne(r); float r2 = r - bf16_f(m);
  l = bf16_rne(r2);
}
// pair split via v_cvt_pk_bf16_f32 (verified on gfx950: dst = {lo=cvt(src0),
// hi=cvt(src1)}; split-3 residual planes absorb any tie-rounding delta)
__device__ __forceinline__ void split3_pk(float x, float y,
                                          unsigned& ph, unsigned& pm, unsigned& pl) {
  asm("v_cvt_pk_bf16_f32 %0, %1, %2" : "=v"(ph) : "v"(x), "v"(y));
  float xh = __builtin_bit_cast(float, ph << 16);
  float yh = __builtin_bit_cast(float, ph & 0xFFFF0000u);
  float rx = x - xh, ry = y - yh;
  asm("v_cvt_pk_bf16_f32 %0, %1, %2" : "=v"(pm) : "v"(rx), "v"(ry));
  float xm = __builtin_bit_cast(float, pm << 16);
  float ym = __builtin_bit_cast(float, pm & 0xFFFF0000u);
  float r2x = rx - xm, r2y = ry - ym;
  asm("v_cvt_pk_bf16_f32 %0, %1, %2" : "=v"(pl) : "v"(r2x), "v"(r2y));
}

// Raw workgroup barrier that waits ONLY on LDS (lgkmcnt), not on in-flight
// global stores (vmcnt). __syncthreads() would drain vmcnt(0) at every
// barrier; our global stores (feature/Y) are only read back at the NEXT
// node's phase0, which sits behind the one full __syncthreads() per node.
__device__ __forceinline__ void bar_lgkm() {
  __builtin_amdgcn_sched_barrier(0);
  asm volatile("s_waitcnt lgkmcnt(0)" ::: "memory");
  __builtin_amdgcn_s_barrier();
  asm volatile("" ::: "memory");
  __builtin_amdgcn_sched_barrier(0);
}

// ---------------------------------------------------------------------------
// K1: G0 = X @ W_emb (f64 accumulation), feat0 = relu(G0 + b_emb), out=feat0
// ---------------------------------------------------------------------------
__global__ __launch_bounds__(256) void k_embed(
    const float* __restrict__ X, const float* __restrict__ W_emb,
    const float* __restrict__ b_emb,
    float* __restrict__ G0, float* __restrict__ feat0, float* __restrict__ out)
{
  const int t = threadIdx.x;
  const int j = t & 63;
  const int node = (blockIdx.x << 2) + (t >> 6);
  const float* __restrict__ xr = X + (size_t)node * 8192;
  const float* __restrict__ wp = W_emb + j;
  double a0 = 0.0, a1 = 0.0, a2 = 0.0, a3 = 0.0;
  for (int f = 0; f < 8192; f += 4) {
    float x0 = xr[f + 0], x1 = xr[f + 1], x2 = xr[f + 2], x3 = xr[f + 3];
    a0 = fma((double)x0, (double)wp[(f + 0) << 6], a0);
    a1 = fma((double)x1, (double)wp[(f + 1) << 6], a1);
    a2 = fma((double)x2, (double)wp[(f + 2) << 6], a2);
    a3 = fma((double)x3, (double)wp[(f + 3) << 6], a3);
  }
  float g = (float)((a0 + a1) + (a2 + a3));
  const int o = node * 64 + j;
  G0[o] = g;
  float f0 = fmaxf(g + b_emb[j], 0.0f);
  feat0[o] = f0;
  out[o] = f0;
}

// ---------------------------------------------------------------------------
// K2: Y0 = feat0 @ W1b (W1 rows 64..127); Y = Y0 working copy
// ---------------------------------------------------------------------------
__global__ __launch_bounds__(128) void k_y0(
    const float* __restrict__ feat0, const float* __restrict__ W1,
    float* __restrict__ Y0, float* __restrict__ Y)
{
  const int c = threadIdx.x;
  const int i = blockIdx.x;
  const float* __restrict__ fr = feat0 + i * 64;
  float acc = 0.0f;
  #pragma unroll 8
  for (int e = 0; e < 64; ++e)
    acc = fmaf(fr[e], W1[(64 + e) * 128 + c], acc);
  Y0[i * 128 + c] = acc;
  Y[i * 128 + c] = acc;
}

// ---------------------------------------------------------------------------
// K3: serial chain, 512 threads / 8 waves. MFMA B2.
// Round-12: all in-node barriers are lgkm-only raw barriers; ONE full
// __syncthreads() per node (before phase0) drains the global stores from the
// previous node's D/E phases. All arithmetic byte-identical to round 11.
// ---------------------------------------------------------------------------
__global__ __launch_bounds__(512, 2) void k_serial(
    const int* __restrict__ neighbors,
    const float* __restrict__ W1, const float* __restrict__ b1,
    const float* __restrict__ W2, const float* __restrict__ b2,
    const float* __restrict__ W_lk, const float* __restrict__ b_lk,
    const float* __restrict__ W_act, const float* __restrict__ b_act,
    const float* __restrict__ b_emb,
    const float* __restrict__ G0, const float* __restrict__ feat0,
    const float* __restrict__ Y0, float* __restrict__ Y,
    float* __restrict__ feature)   // == d_out
{
  __shared__ __align__(16) float W1T[128 * 130];            // 66.6 KB full W1^T
  __shared__ __align__(16) unsigned short Ash[48 * 128];    // 12 KB h1 hi plane
  __shared__ __align__(16) unsigned short Asm[48 * 128];    // 12 KB h1 mid plane
  __shared__ __align__(16) unsigned short Asl[48 * 128];    // 12 KB h1 lo plane
  __shared__ __align__(16) float Yl[32][128];               // 16 KB
  __shared__ __align__(16) float G0l[32][64];               // 8 KB
  __shared__ __align__(16) float a1s[128];
  __shared__ __align__(16) float fis[64];
  __shared__ __align__(16) float b1s[128];
  __shared__ __align__(16) float lkrawT[16][64];            // 4 KB  [c=(mt,lg)][row]
  __shared__ __align__(16) f32x2 p01rawT[16][32];           // 4 KB  [c][row<32]
  __shared__ __align__(16) unsigned keybuf[64];
  __shared__ int idxs[32];
  __shared__ int s_u, s_upd;
  __shared__ unsigned s_mu, s_mi;

  const int t = threadIdx.x;
  const int lane = t & 63;
  const int wave = t >> 6;
  const int l15 = lane & 15;
  const int lg = lane >> 4;            // 0..3
  const int mt = wave & 3;             // W2-col tile
  const int m0 = mt << 4;
  const int c16 = (mt << 2) + lg;      // raw-partial column id

  unsigned* const uAsh = (unsigned*)Ash;
  unsigned* const uAsm = (unsigned*)Asm;
  unsigned* const uAsl = (unsigned*)Asl;

  // ---- one-time staging: full transposed W1 (coalesced global reads) ----
  for (int idx = t; idx < 16384; idx += 512) {
    int e = idx >> 7, c = idx & 127;     // consecutive lanes -> consecutive c
    W1T[c * 130 + e] = W1[e * 128 + c];
  }
  if (t < 128) b1s[t] = b1[t];
  for (int idx = 33 * 64 + t; idx < 48 * 64; idx += 512) {  // zero pad rows
    uAsh[idx] = 0u; uAsm[idx] = 0u; uAsl[idx] = 0u;
  }
  const float blkv = b_lk[0];
  const float ba0 = b_act[0];
  const float ba1 = b_act[1];
  const float bembr = b_emb[lane];
  // W2^T A-frags split-3 in VGPRs: col = m0+l15, k = 32kc + 8lg + e
  bf16x8 wh[4], wm[4], wl[4];
  #pragma unroll
  for (int kc = 0; kc < 4; ++kc) {
    bf16x8 vh, vm, vl;
    #pragma unroll
    for (int e = 0; e < 8; ++e) {
      int k = (kc << 5) + (lg << 3) + e;
      float x = W2[k * 64 + m0 + l15];
      unsigned short sh, sm, sl;
      split3(x, sh, sm, sl);
      vh[e] = (short)sh; vm[e] = (short)sm; vl[e] = (short)sl;
    }
    wh[kc] = vh; wm[kc] = vm; wl[kc] = vl;
  }
  // hoisted epilogue constants
  const f32x4 c0init = *(const f32x4*)&b2[m0 + (lg << 2)];
  const f32x4 wl4 = *(const f32x4*)&W_lk[m0 + (lg << 2)];
  f32x4 wa0v, wa1v;
  #pragma unroll
  for (int r = 0; r < 4; ++r) {
    f32x2 w2a = *(const f32x2*)&W_act[(m0 + (lg << 2) + r) << 1];
    wa0v[r] = w2a[0]; wa1v[r] = w2a[1];
  }
  // hoisted B1 constants
  int kk[4]; unsigned wb[4]; const float2* ylp[4];
  #pragma unroll
  for (int n = 0; n < 4; ++n) {
    kk[n] = wave + (n << 3);
    wb[n] = (unsigned)((kk[n] << 6) + (lane ^ ((kk[n] & 7) << 2)));
    ylp[n] = (const float2*)&Yl[kk[n]][lane << 1];
  }
  const unsigned wb32 = 2048u + (unsigned)lane;   // row 32, swz=0
  // hoisted B2 read offsets (ushort units)
  const int ntA = (wave < 4) ? 0 : 1;
  const int rowA = (ntA << 4) + l15;
  const int rowB = 32 + l15;                       // only waves 0-3
  int aoA[4], aoB[4];
  #pragma unroll
  for (int kc = 0; kc < 4; ++kc) {
    aoA[kc] = (rowA << 7) + ((((kc << 2) + lg) ^ (rowA & 7)) << 3);
    aoB[kc] = (rowB << 7) + ((((kc << 2) + lg) ^ (rowB & 7)) << 3);
  }
  const float2* const a1p = (const float2*)&a1s[lane << 1];
  // wave-0 register state
  unsigned vm = 0xFFFFFFFFu; float cntf = 0.f; int done = 0;
  int ridx = 0; float gisr = 0.f, sumgr = 0.f;

  for (int i = 0; i < 1024; ++i) {
    // ---- full drain once per node: prior node's feature/Y stores must be
    //      visible to this node's phase0 loads ----
    __syncthreads();
    // ---- phase0: per-node prefetch ----
    #pragma unroll
    for (int p = 0; p < 2; ++p) {
      int fi = (p << 9) + t;               // 0..1023
      int k = fi >> 5;
      int c4 = (fi & 31) << 2;
      int v = neighbors[(i << 5) + k];
      *(float4*)&Yl[k][c4] = *(const float4*)&Y[v * 128 + c4];
    }
    {
      int k = t >> 4;                      // 0..31
      int c4 = (t & 15) << 2;
      int v = neighbors[(i << 5) + k];
      *(float4*)&G0l[k][c4] = *(const float4*)&G0[v * 64 + c4];
    }
    if (t < 64) fis[t] = feature[(i << 6) + t];
    if (t < 32) idxs[t] = neighbors[(i << 5) + t];
    bar_lgkm();
    // ---- a1 = fi @ W1a + b1 (W1T b64 reads; chain bit-identical) ----
    if (t < 128) {
      float aa0 = b1s[t], aa1 = 0.0f;
      const float* w1r = &W1T[t * 130];
      #pragma unroll 8
      for (int e = 0; e < 64; e += 2) {
        f32x2 wv = *(const f32x2*)&w1r[e];
        aa0 = fmaf(fis[e],     wv[0], aa0);
        aa1 = fmaf(fis[e + 1], wv[1], aa1);
      }
      a1s[t] = aa0 + aa1;
    }
    int vn[4];
    #pragma unroll
    for (int n = 0; n < 4; ++n) vn[n] = idxs[kk[n]];
    if (wave == 0) {
      ridx = idxs[lane & 31];
      gisr = G0[(i << 6) + lane];
      sumgr = 0.f; vm = 0xFFFFFFFFu; cntf = 0.f; done = 0;
    }
    bar_lgkm();

    for (int st = 0; st < 3; ++st) {
      // ---- B1: 4 rows/wave (+row 32 by wave 4); cvt_pk split-3 ----
      {
        float2 av = *a1p;
        #pragma unroll
        for (int n = 0; n < 4; ++n) {
          float hx = av.x, hy = av.y;
          if (vn[n] > 0) {                         // wave-uniform branch
            float2 yv = *ylp[n];
            hx += yv.x; hy += yv.y;
          }
          hx = fmaxf(hx, 0.f); hy = fmaxf(hy, 0.f);
          unsigned ph, pm, pl;
          split3_pk(hx, hy, ph, pm, pl);
          uAsh[wb[n]] = ph; uAsm[wb[n]] = pm; uAsl[wb[n]] = pl;
        }
        if (wave == 4) {
          float hx = fmaxf(av.x, 0.f), hy = fmaxf(av.y, 0.f);
          unsigned ph, pm, pl;
          split3_pk(hx, hy, ph, pm, pl);
          uAsh[wb32] = ph; uAsm[wb32] = pm; uAsl[wb32] = pl;
        }
      }
      bar_lgkm();
      // ---- B2: MFMA tiles (waves 0-3: rows 0-15 & 32-47; waves 4-7: 16-31) --
      {
        f32x4 cA = c0init, cB = c0init;
        const bool twoT = (wave < 4);
        #pragma unroll
        for (int kc = 0; kc < 4; ++kc) {
          bf16x8 ahA = *(const bf16x8*)&Ash[aoA[kc]];
          bf16x8 amA = *(const bf16x8*)&Asm[aoA[kc]];
          bf16x8 alA = *(const bf16x8*)&Asl[aoA[kc]];
          cA = __builtin_amdgcn_mfma_f32_16x16x32_bf16(wh[kc], ahA, cA, 0, 0, 0);
          cA = __builtin_amdgcn_mfma_f32_16x16x32_bf16(wh[kc], amA, cA, 0, 0, 0);
          cA = __builtin_amdgcn_mfma_f32_16x16x32_bf16(wm[kc], ahA, cA, 0, 0, 0);
          cA = __builtin_amdgcn_mfma_f32_16x16x32_bf16(wh[kc], alA, cA, 0, 0, 0);
          cA = __builtin_amdgcn_mfma_f32_16x16x32_bf16(wl[kc], ahA, cA, 0, 0, 0);
          cA = __builtin_amdgcn_mfma_f32_16x16x32_bf16(wm[kc], amA, cA, 0, 0, 0);
          if (twoT) {
            bf16x8 ahB = *(const bf16x8*)&Ash[aoB[kc]];
            bf16x8 amB = *(const bf16x8*)&Asm[aoB[kc]];
            bf16x8 alB = *(const bf16x8*)&Asl[aoB[kc]];
            cB = __builtin_amdgcn_mfma_f32_16x16x32_bf16(wh[kc], ahB, cB, 0, 0, 0);
            cB = __builtin_amdgcn_mfma_f32_16x16x32_bf16(wh[kc], amB, cB, 0, 0, 0);
            cB = __builtin_amdgcn_mfma_f32_16x16x32_bf16(wm[kc], ahB, cB, 0, 0, 0);
            cB = __builtin_amdgcn_mfma_f32_16x16x32_bf16(wh[kc], alB, cB, 0, 0, 0);
            cB = __builtin_amdgcn_mfma_f32_16x16x32_bf16(wl[kc], ahB, cB, 0, 0, 0);
            cB = __builtin_amdgcn_mfma_f32_16x16x32_bf16(wm[kc], amB, cB, 0, 0, 0);
          }
        }
        // epilogue A: raw per-lg partials (no shfl)
        {
          float pl = 0.f, q0 = 0.f, q1 = 0.f;
          #pragma unroll
          for (int r = 0; r < 4; ++r) {
            float v = fmaxf(cA[r], 0.f);
            pl = fmaf(v, wl4[r], pl);
            q0 = fmaf(v, wa0v[r], q0);
            q1 = fmaf(v, wa1v[r], q1);
          }
          lkrawT[c16][rowA] = pl;
          p01rawT[c16][rowA] = (f32x2){q0, q1};
        }
        if (twoT) {   // row 32 never feeds the action head: lk partial only
          float pl = 0.f;
          #pragma unroll
          for (int r = 0; r < 4; ++r) {
            float v = fmaxf(cB[r], 0.f);
            pl = fmaf(v, wl4[r], pl);
          }
          lkrawT[c16][rowB] = pl;
        }
      }
      bar_lgkm();
      // ---- P4+D (wave 0): assemble lk (bit-identical nesting), LDS-key
      //      argmax (no shfl chain), action head, state update ----
      if (wave == 0) {
        float v_[16];
        #pragma unroll
        for (int c = 0; c < 16; ++c) v_[c] = lkrawT[c][lane];
        float s0 = (v_[0] + v_[1]) + (v_[2] + v_[3]);
        float s1 = (v_[4] + v_[5]) + (v_[6] + v_[7]);
        float s2 = (v_[8] + v_[9]) + (v_[10] + v_[11]);
        float s3 = (v_[12] + v_[13]) + (v_[14] + v_[15]);
        float lkv = ((s0 + s1) + (s2 + s3)) + blkv;
        unsigned b = __builtin_bit_cast(unsigned, lkv);
        int sb = (int)b >> 31;
        unsigned mono = b ^ (0x80000000u | (unsigned)sb);
        bool valid = (lane == 32) || ((lane < 32) && ((vm >> lane) & 1u));
        unsigned key = valid ? mono : 0u;
        keybuf[lane] = key;
        asm volatile("s_waitcnt lgkmcnt(0)" ::: "memory");
        __builtin_amdgcn_sched_barrier(0);
        const uint4* kb = (const uint4*)keybuf;
        unsigned mx = 0u;
        #pragma unroll
        for (int c = 0; c < 16; ++c) {
          uint4 kv = kb[c];
          unsigned m01 = kv.x > kv.y ? kv.x : kv.y;
          unsigned m23 = kv.z > kv.w ? kv.z : kv.w;
          unsigned mm = m01 > m23 ? m01 : m23;
          mx = mx > mm ? mx : mm;
        }
        unsigned long long am = __ballot(valid && (key == mx));
        const int ut = (int)(__ffsll(am) - 1);
        const int utc = ut < 31 ? ut : 31;
        // action head: broadcast reads of raw partials at utc, same nesting
        f32x2 q[16];
        #pragma unroll
        for (int c = 0; c < 16; ++c) q[c] = p01rawT[c][utc];
        f32x2 S0 = (q[0] + q[1]) + (q[2] + q[3]);
        f32x2 S1 = (q[4] + q[5]) + (q[6] + q[7]);
        f32x2 S2 = (q[8] + q[9]) + (q[10] + q[11]);
        f32x2 S3 = (q[12] + q[13]) + (q[14] + q[15]);
        f32x2 D01 = (S0 + S1) + (S2 + S3);
        float d0 = D01[0] + ba0;
        float d1 = D01[1] + ba1;
        const int at1 = (d1 > d0) ? 1 : 0;
        const int newdone = done | (ut == 32);
        const int upd = newdone ? 0 : 1;
        done = newdone;
        const float take = at1 ? 1.0f : 0.0f;
        const float denom = cntf + take + 1.0f;
        const int u = __builtin_amdgcn_readlane(ridx, utc);
        unsigned long long bu = __ballot(lane < 32 && ridx == u);
        unsigned long long bi = __ballot(lane < 32 && ridx == i);
        if (lane == 0) {
          s_u = u; s_upd = upd;
          s_mu = (unsigned)bu; s_mi = (unsigned)bi;
        }
        if (upd) {
          vm &= ~(1u << utc);
          cntf += take;
          const float gu = G0l[utc][lane];
          const float ns = sumgr + take * gu;
          const float hv = (ns + gisr) / denom;
          const float nfi = fmaxf(hv + bembr, 0.0f);
          sumgr = ns;
          const float f0u = fmaxf(gu + bembr, 0.0f);   // == feat0[u] bit-exact
          feature[(i << 6) + lane] = nfi;              // feature[u] wins if u==i
          feature[(u << 6) + lane] = f0u;
          fis[lane] = (u == i) ? f0u : nfi;
        }
      }
      bar_lgkm();
      if (!s_upd) break;
      // ---- E: waves 0-1 -> Y rows + Yl patches; waves 2-3 -> a1 ----
      if (wave < 4) {
        const int u = s_u;
        const int c = t & 127;
        const float* w1r = &W1T[c * 130];
        if (wave < 2) {
          const float yu = Y0[u * 128 + c];            // early, overlaps FMAs
          f32x2 acc = {0.f, 0.f};
          #pragma unroll 8
          for (int e = 0; e < 64; e += 2) {
            f32x2 fv = *(const f32x2*)&fis[e];
            f32x2 wv = *(const f32x2*)&w1r[64 + e];
            acc = __builtin_elementwise_fma(fv, wv, acc);
          }
          const float yi = acc[0] + acc[1];
          Y[i * 128 + c] = yi;                         // Y[u] wins if u==i
          Y[u * 128 + c] = yu;
          const unsigned mu = s_mu;
          for (unsigned m = mu; m; m &= m - 1) {
            int k = __ffs(m) - 1;
            Yl[k][c] = yu;
          }
          for (unsigned m = s_mi & ~mu; m; m &= m - 1) {
            int k = __ffs(m) - 1;
            Yl[k][c] = yi;
          }
        } else {
          f32x2 aa = {b1s[c], 0.f};
          #pragma unroll 8
          for (int e = 0; e < 64; e += 2) {
            f32x2 fv = *(const f32x2*)&fis[e];
            f32x2 wv = *(const f32x2*)&w1r[e];
            aa = __builtin_elementwise_fma(fv, wv, aa);
          }
          a1s[c] = aa[0] + aa[1];
        }
      }
      bar_lgkm();
    }
  }
}

// ---------------------------------------------------------------------------
extern "C" void kernel_launch(void* const* d_in, const int* in_sizes, int n_in,
                              void* d_out, int out_size, void* d_ws, size_t ws_size,
                              hipStream_t stream) {
  const float* X     = (const float*)d_in[0];
  const int*   nbr   = (const int*)  d_in[1];
  const float* W_emb = (const float*)d_in[2];
  const float* b_emb = (const float*)d_in[3];
  const float* W1    = (const float*)d_in[4];
  const float* b1    = (const float*)d_in[5];
  const float* W2    = (const float*)d_in[6];
  const float* b2    = (const float*)d_in[7];
  const float* W_lk  = (const float*)d_in[8];
  const float* b_lk  = (const float*)d_in[9];
  const float* W_act = (const float*)d_in[10];
  const float* b_act = (const float*)d_in[11];
  float* out = (float*)d_out;
  float* ws  = (float*)d_ws;
  float* G0    = ws;             // [1024*64]
  float* feat0 = ws + 65536;     // [1024*64]
  float* Y0    = ws + 131072;    // [1024*128]
  float* Y     = ws + 262144;    // [1024*128]

  hipLaunchKernelGGL(k_embed, dim3(256), dim3(256), 0, stream,
                     X, W_emb, b_emb, G0, feat0, out);
  hipLaunchKernelGGL(k_y0, dim3(1024), dim3(128), 0, stream,
                     feat0, W1, Y0, Y);
  hipLaunchKernelGGL(k_serial, dim3(1), dim3(512), 0, stream,
                     nbr, W1, b1, W2, b2, W_lk, b_lk, W_act, b_act, b_emb,
                     G0, feat0, Y0, Y, out);
}